// Round 1
// baseline (1150.160 us; speedup 1.0000x reference)
//
#include <hip/hip_runtime.h>
#include <math.h>

#define N_NODES 50000
#define E_EDGES 600000
#define IN_DIM  384
#define HID     128
#define HYP     256

typedef __attribute__((ext_vector_type(8))) short bf16x8;
typedef __attribute__((ext_vector_type(4))) float f32x4;

__device__ __forceinline__ unsigned short f2bf(float f) {
    unsigned u = __builtin_bit_cast(unsigned, f);
    u = (u + 0x7FFFu + ((u >> 16) & 1u)) >> 16;
    return (unsigned short)u;
}

__device__ __forceinline__ bf16x8 cvt8(float4 p, float4 q) {
    bf16x8 a;
    a[0] = (short)f2bf(p.x); a[1] = (short)f2bf(p.y);
    a[2] = (short)f2bf(p.z); a[3] = (short)f2bf(p.w);
    a[4] = (short)f2bf(q.x); a[5] = (short)f2bf(q.y);
    a[6] = (short)f2bf(q.z); a[7] = (short)f2bf(q.w);
    return a;
}

// ---------------- graph preprocessing ----------------

__global__ void k_deg(const int* __restrict__ dst, int* __restrict__ deg) {
    int i = blockIdx.x * blockDim.x + threadIdx.x;
    if (i < E_EDGES) atomicAdd(&deg[dst[i]], 1);
}

__global__ __launch_bounds__(1024) void k_scan(const int* __restrict__ deg, int* __restrict__ row_start,
                                               float* __restrict__ dinv) {
    __shared__ int part[1024];
    int tid = threadIdx.x;
    const int chunk = (N_NODES + 1023) >> 10;  // 49
    int s = tid * chunk;
    int e = min(N_NODES, s + chunk);
    int sum = 0;
    for (int i = s; i < e; ++i) sum += deg[i];
    part[tid] = sum;
    __syncthreads();
    for (int off = 1; off < 1024; off <<= 1) {
        int t = (tid >= off) ? part[tid - off] : 0;
        __syncthreads();
        part[tid] += t;
        __syncthreads();
    }
    int base = part[tid] - sum;  // exclusive prefix
    for (int i = s; i < e; ++i) {
        int d = deg[i];
        row_start[i] = base;
        base += d;
        dinv[i] = (d > 0) ? rsqrtf((float)d) : 0.0f;
    }
    if (tid == 0) row_start[N_NODES] = E_EDGES;
}

__global__ void k_fill(const int* __restrict__ src, const int* __restrict__ dst,
                       const int* __restrict__ row_start, int* __restrict__ cnt,
                       const float* __restrict__ dinv,
                       int* __restrict__ csr_src, float* __restrict__ csr_w) {
    int i = blockIdx.x * blockDim.x + threadIdx.x;
    if (i < E_EDGES) {
        int d = dst[i], s = src[i];
        int pos = row_start[d] + atomicAdd(&cnt[d], 1);
        csr_src[pos] = s;
        csr_w[pos] = dinv[s] * dinv[d];
    }
}

// ---------------- transpose + fp32->bf16 convert: out[c][r] = bf16(in[r][c]) ----------------

__global__ void k_cvtT(const float* __restrict__ in, unsigned short* __restrict__ out, int R, int C) {
    int i = blockIdx.x * 256 + threadIdx.x;
    if (i < R * C) {
        int r = i / C;
        int c = i - r * C;
        out[(size_t)c * R + r] = f2bf(in[i]);
    }
}

// ---------------- x_emb = x @ w_feat + b : MFMA, 1 wave/block, 16 rows ----------------

__global__ __launch_bounds__(64) void k_emb(const float* __restrict__ x, const unsigned short* __restrict__ wfT,
                                            const float* __restrict__ bf_,
                                            float* __restrict__ x_emb, float* __restrict__ accb) {
    int lane = threadIdx.x & 63;
    int l16 = lane & 15, quad = lane >> 4;
    int m0 = blockIdx.x * 16;
    const float* xrow = x + (size_t)(m0 + l16) * IN_DIM + quad * 8;
    f32x4 acc[8];
#pragma unroll
    for (int nt = 0; nt < 8; ++nt) acc[nt] = (f32x4){0.f, 0.f, 0.f, 0.f};
#pragma unroll
    for (int kt = 0; kt < IN_DIM / 32; ++kt) {
        float4 p = *reinterpret_cast<const float4*>(xrow + kt * 32);
        float4 q = *reinterpret_cast<const float4*>(xrow + kt * 32 + 4);
        bf16x8 a = cvt8(p, q);
#pragma unroll
        for (int nt = 0; nt < 8; ++nt) {
            bf16x8 b = *reinterpret_cast<const bf16x8*>(&wfT[(size_t)(nt * 16 + l16) * IN_DIM + kt * 32 + quad * 8]);
            acc[nt] = __builtin_amdgcn_mfma_f32_16x16x32_bf16(a, b, acc[nt], 0, 0, 0);
        }
    }
#pragma unroll
    for (int nt = 0; nt < 8; ++nt) {
        int col = nt * 16 + l16;
        float bias = bf_[col];
#pragma unroll
        for (int r = 0; r < 4; ++r) {
            int row = m0 + quad * 4 + r;
            float v = acc[nt][r] + bias;
            size_t o = (size_t)row * HID + col;
            x_emb[o] = v;
            accb[o] = v;
        }
    }
}

// ---------------- one LightGCN layer (unchanged fp32 gather) ----------------

__device__ __forceinline__ void fma4(float4& a, const float4& v, float s) {
    a.x = fmaf(v.x, s, a.x);
    a.y = fmaf(v.y, s, a.y);
    a.z = fmaf(v.z, s, a.z);
    a.w = fmaf(v.w, s, a.w);
}

__global__ __launch_bounds__(128) void k_prop(const float* __restrict__ cur, float* __restrict__ nxt,
                                              float* __restrict__ accb,
                                              const int* __restrict__ row_start,
                                              const int* __restrict__ csr_src, const float* __restrict__ csr_w) {
    int tid = threadIdx.x;
    int n = blockIdx.x * 4 + (tid >> 5);
    int c4 = (tid & 31) * 4;
    int s = row_start[n];
    int e = row_start[n + 1];
    float4 a0 = {0.f, 0.f, 0.f, 0.f}, a1 = a0, a2 = a0, a3 = a0;
    int i = s;
    for (; i + 4 <= e; i += 4) {
        int s0 = csr_src[i], s1 = csr_src[i + 1], s2 = csr_src[i + 2], s3 = csr_src[i + 3];
        float w0 = csr_w[i], w1 = csr_w[i + 1], w2 = csr_w[i + 2], w3 = csr_w[i + 3];
        float4 v0 = *reinterpret_cast<const float4*>(&cur[(size_t)s0 * HID + c4]);
        float4 v1 = *reinterpret_cast<const float4*>(&cur[(size_t)s1 * HID + c4]);
        float4 v2 = *reinterpret_cast<const float4*>(&cur[(size_t)s2 * HID + c4]);
        float4 v3 = *reinterpret_cast<const float4*>(&cur[(size_t)s3 * HID + c4]);
        fma4(a0, v0, w0); fma4(a1, v1, w1); fma4(a2, v2, w2); fma4(a3, v3, w3);
    }
    for (; i < e; ++i) {
        int s0 = csr_src[i];
        float w0 = csr_w[i];
        float4 v0 = *reinterpret_cast<const float4*>(&cur[(size_t)s0 * HID + c4]);
        fma4(a0, v0, w0);
    }
    a0.x += a1.x + a2.x + a3.x;
    a0.y += a1.y + a2.y + a3.y;
    a0.z += a1.z + a2.z + a3.z;
    a0.w += a1.w + a2.w + a3.w;
    size_t o = (size_t)n * HID + c4;
    *reinterpret_cast<float4*>(&nxt[o]) = a0;
    float4 ac = *reinterpret_cast<const float4*>(&accb[o]);
    ac.x += a0.x; ac.y += a0.y; ac.z += a0.z; ac.w += a0.w;
    *reinterpret_cast<float4*>(&accb[o]) = ac;
}

// ---------------- Hm = softmax((x_emb @ w_hyper + g)/tau) : MFMA, 1 wave/block ----------------

__global__ __launch_bounds__(64) void k_soft(const float* __restrict__ x_emb, const unsigned short* __restrict__ whT,
                                             const float* __restrict__ gu, float* __restrict__ Hm) {
    int lane = threadIdx.x & 63;
    int l16 = lane & 15, quad = lane >> 4;
    int m0 = blockIdx.x * 16;
    const float* xrow = x_emb + (size_t)(m0 + l16) * HID + quad * 8;
    f32x4 acc[16];
#pragma unroll
    for (int nt = 0; nt < 16; ++nt) acc[nt] = (f32x4){0.f, 0.f, 0.f, 0.f};
#pragma unroll
    for (int kt = 0; kt < HID / 32; ++kt) {
        float4 p = *reinterpret_cast<const float4*>(xrow + kt * 32);
        float4 q = *reinterpret_cast<const float4*>(xrow + kt * 32 + 4);
        bf16x8 a = cvt8(p, q);
#pragma unroll
        for (int nt = 0; nt < 16; ++nt) {
            bf16x8 b = *reinterpret_cast<const bf16x8*>(&whT[(size_t)(nt * 16 + l16) * HID + kt * 32 + quad * 8]);
            acc[nt] = __builtin_amdgcn_mfma_f32_16x16x32_bf16(a, b, acc[nt], 0, 0, 0);
        }
    }
    // gumbel + 1/tau
#pragma unroll
    for (int nt = 0; nt < 16; ++nt) {
        int col = nt * 16 + l16;
#pragma unroll
        for (int r = 0; r < 4; ++r) {
            int row = m0 + quad * 4 + r;
            float u = gu[(size_t)row * HYP + col];
            float g = -logf(-logf(u + 1e-10f) + 1e-10f);
            acc[nt][r] = (acc[nt][r] + g) * 2.0f;
        }
    }
    // row max / sum over cols: per-lane over nt, then shfl over lane&15 group
    float mx[4] = {-3.4e38f, -3.4e38f, -3.4e38f, -3.4e38f};
#pragma unroll
    for (int nt = 0; nt < 16; ++nt)
#pragma unroll
        for (int r = 0; r < 4; ++r) mx[r] = fmaxf(mx[r], acc[nt][r]);
#pragma unroll
    for (int r = 0; r < 4; ++r) {
        mx[r] = fmaxf(mx[r], __shfl_xor(mx[r], 1));
        mx[r] = fmaxf(mx[r], __shfl_xor(mx[r], 2));
        mx[r] = fmaxf(mx[r], __shfl_xor(mx[r], 4));
        mx[r] = fmaxf(mx[r], __shfl_xor(mx[r], 8));
    }
    float sm[4] = {0.f, 0.f, 0.f, 0.f};
#pragma unroll
    for (int nt = 0; nt < 16; ++nt)
#pragma unroll
        for (int r = 0; r < 4; ++r) {
            float e = __expf(acc[nt][r] - mx[r]);
            acc[nt][r] = e;
            sm[r] += e;
        }
#pragma unroll
    for (int r = 0; r < 4; ++r) {
        sm[r] += __shfl_xor(sm[r], 1);
        sm[r] += __shfl_xor(sm[r], 2);
        sm[r] += __shfl_xor(sm[r], 4);
        sm[r] += __shfl_xor(sm[r], 8);
        sm[r] = 1.0f / sm[r];
    }
#pragma unroll
    for (int nt = 0; nt < 16; ++nt) {
        int col = nt * 16 + l16;
#pragma unroll
        for (int r = 0; r < 4; ++r)
            Hm[(size_t)(m0 + quad * 4 + r) * HYP + col] = acc[nt][r] * sm[r];
    }
}

// ---------------- lat = Hm^T @ x_emb : barrier-free register-tiled outer product, split-K ----------------
// grid = 2 * KC blocks; bx&1 selects h-half (128 of 256), bx>>1 selects K-chunk.
// Each thread owns an 8h x 8d accumulator; per node: 4 float4 loads + 64 FMAs, no LDS, no syncs.
// Hm read exactly once from global (h-halves disjoint), x_emb read twice.

#define LAT_KC 384

__global__ __launch_bounds__(256) void k_lat(const float* __restrict__ Hm, const float* __restrict__ x_emb,
                                             float* __restrict__ lat) {
    int htile = blockIdx.x & 1;
    int kc = blockIdx.x >> 1;
    const int chunk = (N_NODES + LAT_KC - 1) / LAT_KC;  // 131
    int start = kc * chunk;
    if (start >= N_NODES) return;
    int end = min(N_NODES, start + chunk);
    int nn = end - start;
    int tid = threadIdx.x;
    int h = htile * 128 + (tid & 15) * 8;  // 8 consecutive h per thread
    int d = (tid >> 4) * 8;                // 8 consecutive d per thread
    const float* __restrict__ hp = Hm + (size_t)start * HYP + h;
    const float* __restrict__ xp = x_emb + (size_t)start * HID + d;
    float acc[8][8];
#pragma unroll
    for (int i = 0; i < 8; ++i)
#pragma unroll
        for (int j = 0; j < 8; ++j) acc[i][j] = 0.f;
#pragma unroll 2
    for (int n = 0; n < nn; ++n) {
        float4 a0 = *reinterpret_cast<const float4*>(hp);
        float4 a1 = *reinterpret_cast<const float4*>(hp + 4);
        float4 b0 = *reinterpret_cast<const float4*>(xp);
        float4 b1 = *reinterpret_cast<const float4*>(xp + 4);
        float av[8] = {a0.x, a0.y, a0.z, a0.w, a1.x, a1.y, a1.z, a1.w};
        float bv[8] = {b0.x, b0.y, b0.z, b0.w, b1.x, b1.y, b1.z, b1.w};
#pragma unroll
        for (int i = 0; i < 8; ++i)
#pragma unroll
            for (int j = 0; j < 8; ++j) acc[i][j] = fmaf(av[i], bv[j], acc[i][j]);
        hp += HYP;
        xp += HID;
    }
#pragma unroll
    for (int i = 0; i < 8; ++i)
#pragma unroll
        for (int j = 0; j < 8; ++j)
            atomicAdd(&lat[(size_t)(h + i) * HID + (d + j)], acc[i][j]);
}

// ---------------- tail: hyper = Hm @ lat; norm; final; two head GEMMs — MFMA, 1 wave/block ----------------

__global__ __launch_bounds__(64) void k_tail(const float* __restrict__ Hm, const unsigned short* __restrict__ latT,
                                             const float* __restrict__ accb,
                                             const unsigned short* __restrict__ wvT, const float* __restrict__ bv,
                                             const unsigned short* __restrict__ wtT, const float* __restrict__ bt,
                                             float* __restrict__ out_final, float* __restrict__ out_vis,
                                             float* __restrict__ out_txt) {
    __shared__ unsigned short fl[16 * HID];  // final tile, bf16, 4 KB
    int lane = threadIdx.x & 63;
    int l16 = lane & 15, quad = lane >> 4;
    int m0 = blockIdx.x * 16;
    const float* hrow = Hm + (size_t)(m0 + l16) * HYP + quad * 8;
    f32x4 acc[8];
#pragma unroll
    for (int nt = 0; nt < 8; ++nt) acc[nt] = (f32x4){0.f, 0.f, 0.f, 0.f};
#pragma unroll
    for (int kt = 0; kt < HYP / 32; ++kt) {
        float4 p = *reinterpret_cast<const float4*>(hrow + kt * 32);
        float4 q = *reinterpret_cast<const float4*>(hrow + kt * 32 + 4);
        bf16x8 a = cvt8(p, q);
#pragma unroll
        for (int nt = 0; nt < 8; ++nt) {
            bf16x8 b = *reinterpret_cast<const bf16x8*>(&latT[(size_t)(nt * 16 + l16) * HYP + kt * 32 + quad * 8]);
            acc[nt] = __builtin_amdgcn_mfma_f32_16x16x32_bf16(a, b, acc[nt], 0, 0, 0);
        }
    }
    // per-row L2 norm: rows = m0 + quad*4 + r; reduce over cols = nt x (lane&15)
    float ss[4] = {0.f, 0.f, 0.f, 0.f};
#pragma unroll
    for (int nt = 0; nt < 8; ++nt)
#pragma unroll
        for (int r = 0; r < 4; ++r) ss[r] = fmaf(acc[nt][r], acc[nt][r], ss[r]);
#pragma unroll
    for (int r = 0; r < 4; ++r) {
        ss[r] += __shfl_xor(ss[r], 1);
        ss[r] += __shfl_xor(ss[r], 2);
        ss[r] += __shfl_xor(ss[r], 4);
        ss[r] += __shfl_xor(ss[r], 8);
        ss[r] = 1.0f / fmaxf(sqrtf(ss[r]), 1e-12f);
    }
    // final = accb/4 + 0.1 * normalized; store + stage bf16 tile for head GEMMs
#pragma unroll
    for (int nt = 0; nt < 8; ++nt) {
        int col = nt * 16 + l16;
#pragma unroll
        for (int r = 0; r < 4; ++r) {
            int lrow = quad * 4 + r;
            size_t o = (size_t)(m0 + lrow) * HID + col;
            float f = accb[o] * 0.25f + 0.1f * (acc[nt][r] * ss[r]);
            out_final[o] = f;
            fl[lrow * HID + col] = f2bf(f);
        }
    }
    __syncthreads();
    // heads: A = final tile (LDS), B = wvT / wtT
    f32x4 av[8], at4[8];
#pragma unroll
    for (int nt = 0; nt < 8; ++nt) {
        av[nt] = (f32x4){0.f, 0.f, 0.f, 0.f};
        at4[nt] = (f32x4){0.f, 0.f, 0.f, 0.f};
    }
#pragma unroll
    for (int kt = 0; kt < HID / 32; ++kt) {
        bf16x8 a = *reinterpret_cast<const bf16x8*>(&fl[l16 * HID + kt * 32 + quad * 8]);
#pragma unroll
        for (int nt = 0; nt < 8; ++nt) {
            bf16x8 b1 = *reinterpret_cast<const bf16x8*>(&wvT[(size_t)(nt * 16 + l16) * HID + kt * 32 + quad * 8]);
            bf16x8 b2 = *reinterpret_cast<const bf16x8*>(&wtT[(size_t)(nt * 16 + l16) * HID + kt * 32 + quad * 8]);
            av[nt] = __builtin_amdgcn_mfma_f32_16x16x32_bf16(a, b1, av[nt], 0, 0, 0);
            at4[nt] = __builtin_amdgcn_mfma_f32_16x16x32_bf16(a, b2, at4[nt], 0, 0, 0);
        }
    }
#pragma unroll
    for (int nt = 0; nt < 8; ++nt) {
        int col = nt * 16 + l16;
        float b1 = bv[col], b2 = bt[col];
#pragma unroll
        for (int r = 0; r < 4; ++r) {
            size_t o = (size_t)(m0 + quad * 4 + r) * HID + col;
            out_vis[o] = fmaxf(av[nt][r] + b1, 0.0f);
            out_txt[o] = fmaxf(at4[nt][r] + b2, 0.0f);
        }
    }
}

// ---------------- launch ----------------

extern "C" void kernel_launch(void* const* d_in, const int* in_sizes, int n_in,
                              void* d_out, int out_size, void* d_ws, size_t ws_size,
                              hipStream_t stream) {
    const float* x      = (const float*)d_in[0];
    const int*   ei     = (const int*)d_in[1];
    const float* gu     = (const float*)d_in[2];
    const float* w_feat = (const float*)d_in[3];
    const float* b_feat = (const float*)d_in[4];
    const float* w_hyp  = (const float*)d_in[5];
    const float* w_vis  = (const float*)d_in[6];
    const float* b_vis  = (const float*)d_in[7];
    const float* w_txt  = (const float*)d_in[8];
    const float* b_txt  = (const float*)d_in[9];
    float* out = (float*)d_out;

    const int* srcv = ei;
    const int* dstv = ei + E_EDGES;

    char* p = (char*)d_ws;
    int*   deg     = (int*)p;   p += (size_t)N_NODES * 4;
    int*   cnt     = (int*)p;   p += (size_t)N_NODES * 4;
    float* lat     = (float*)p; p += (size_t)HYP * HID * 4;
    int*   rs      = (int*)p;   p += (size_t)(N_NODES + 1) * 4;
    float* dinv    = (float*)p; p += (size_t)N_NODES * 4;
    int*   csr_src = (int*)p;   p += (size_t)E_EDGES * 4;
    float* csr_w   = (float*)p; p += (size_t)E_EDGES * 4;
    float* x_emb   = (float*)p; p += (size_t)N_NODES * HID * 4;
    float* bufA    = (float*)p; p += (size_t)N_NODES * HID * 4;
    float* bufB    = (float*)p; p += (size_t)N_NODES * HID * 4;
    float* accb    = (float*)p; p += (size_t)N_NODES * HID * 4;
    float* Hm      = (float*)p; p += (size_t)N_NODES * HYP * 4;
    unsigned short* wfT  = (unsigned short*)p; p += (size_t)HID * IN_DIM * 2;  // [128][384]
    unsigned short* whT  = (unsigned short*)p; p += (size_t)HYP * HID * 2;     // [256][128]
    unsigned short* wvT  = (unsigned short*)p; p += (size_t)HID * HID * 2;     // [128][128]
    unsigned short* wtT  = (unsigned short*)p; p += (size_t)HID * HID * 2;     // [128][128]
    unsigned short* latT = (unsigned short*)p; p += (size_t)HID * HYP * 2;     // [128][256]

    // zero: deg, cnt, lat (contiguous at the head of ws)
    (void)hipMemsetAsync(d_ws, 0, (size_t)(2 * N_NODES + HYP * HID) * 4, stream);

    // weight transposes/converts (independent of graph work)
    k_cvtT<<<(IN_DIM * HID + 255) / 256, 256, 0, stream>>>(w_feat, wfT, IN_DIM, HID);
    k_cvtT<<<(HID * HYP + 255) / 256, 256, 0, stream>>>(w_hyp, whT, HID, HYP);
    k_cvtT<<<(HID * HID + 255) / 256, 256, 0, stream>>>(w_vis, wvT, HID, HID);
    k_cvtT<<<(HID * HID + 255) / 256, 256, 0, stream>>>(w_txt, wtT, HID, HID);

    k_deg<<<(E_EDGES + 255) / 256, 256, 0, stream>>>(dstv, deg);
    k_scan<<<1, 1024, 0, stream>>>(deg, rs, dinv);
    k_fill<<<(E_EDGES + 255) / 256, 256, 0, stream>>>(srcv, dstv, rs, cnt, dinv, csr_src, csr_w);

    k_emb<<<N_NODES / 16, 64, 0, stream>>>(x, wfT, b_feat, x_emb, accb);
    k_prop<<<N_NODES / 4, 128, 0, stream>>>(x_emb, bufA, accb, rs, csr_src, csr_w);
    k_prop<<<N_NODES / 4, 128, 0, stream>>>(bufA, bufB, accb, rs, csr_src, csr_w);
    k_prop<<<N_NODES / 4, 128, 0, stream>>>(bufB, bufA, accb, rs, csr_src, csr_w);
    k_soft<<<N_NODES / 16, 64, 0, stream>>>(x_emb, whT, gu, Hm);
    k_lat<<<2 * LAT_KC, 256, 0, stream>>>(Hm, x_emb, lat);
    k_cvtT<<<(HYP * HID + 255) / 256, 256, 0, stream>>>(lat, latT, HYP, HID);
    k_tail<<<N_NODES / 16, 64, 0, stream>>>(Hm, latT, accb, wvT, b_vis, wtT, b_txt,
                                            out, out + (size_t)N_NODES * HID, out + (size_t)2 * N_NODES * HID);
}

// Round 2
// 800.517 us; speedup vs baseline: 1.4368x; 1.4368x over previous
//
#include <hip/hip_runtime.h>
#include <math.h>

#define N_NODES 50000
#define E_EDGES 600000
#define IN_DIM  384
#define HID     128
#define HYP     256

typedef __attribute__((ext_vector_type(8))) short bf16x8;
typedef __attribute__((ext_vector_type(4))) float f32x4;

__device__ __forceinline__ unsigned short f2bf(float f) {
    unsigned u = __builtin_bit_cast(unsigned, f);
    u = (u + 0x7FFFu + ((u >> 16) & 1u)) >> 16;
    return (unsigned short)u;
}

__device__ __forceinline__ bf16x8 cvt8(float4 p, float4 q) {
    bf16x8 a;
    a[0] = (short)f2bf(p.x); a[1] = (short)f2bf(p.y);
    a[2] = (short)f2bf(p.z); a[3] = (short)f2bf(p.w);
    a[4] = (short)f2bf(q.x); a[5] = (short)f2bf(q.y);
    a[6] = (short)f2bf(q.z); a[7] = (short)f2bf(q.w);
    return a;
}

// ---------------- graph preprocessing ----------------

__global__ void k_deg(const int* __restrict__ dst, int* __restrict__ deg) {
    int i = blockIdx.x * blockDim.x + threadIdx.x;
    if (i < E_EDGES) atomicAdd(&deg[dst[i]], 1);
}

__global__ __launch_bounds__(1024) void k_scan(const int* __restrict__ deg, int* __restrict__ row_start,
                                               float* __restrict__ dinv) {
    __shared__ int part[1024];
    int tid = threadIdx.x;
    const int chunk = (N_NODES + 1023) >> 10;  // 49
    int s = tid * chunk;
    int e = min(N_NODES, s + chunk);
    int sum = 0;
    for (int i = s; i < e; ++i) sum += deg[i];
    part[tid] = sum;
    __syncthreads();
    for (int off = 1; off < 1024; off <<= 1) {
        int t = (tid >= off) ? part[tid - off] : 0;
        __syncthreads();
        part[tid] += t;
        __syncthreads();
    }
    int base = part[tid] - sum;  // exclusive prefix
    for (int i = s; i < e; ++i) {
        int d = deg[i];
        row_start[i] = base;
        base += d;
        dinv[i] = (d > 0) ? rsqrtf((float)d) : 0.0f;
    }
    if (tid == 0) row_start[N_NODES] = E_EDGES;
}

__global__ void k_fill(const int* __restrict__ src, const int* __restrict__ dst,
                       const int* __restrict__ row_start, int* __restrict__ cnt,
                       const float* __restrict__ dinv,
                       int* __restrict__ csr_src, float* __restrict__ csr_w) {
    int i = blockIdx.x * blockDim.x + threadIdx.x;
    if (i < E_EDGES) {
        int d = dst[i], s = src[i];
        int pos = row_start[d] + atomicAdd(&cnt[d], 1);
        csr_src[pos] = s;
        csr_w[pos] = dinv[s] * dinv[d];
    }
}

// ---------------- transpose + fp32->bf16 convert: out[c][r] = bf16(in[r][c]) ----------------

__global__ void k_cvtT(const float* __restrict__ in, unsigned short* __restrict__ out, int R, int C) {
    int i = blockIdx.x * 256 + threadIdx.x;
    if (i < R * C) {
        int r = i / C;
        int c = i - r * C;
        out[(size_t)c * R + r] = f2bf(in[i]);
    }
}

// ---------------- x_emb = x @ w_feat + b : MFMA, 1 wave/block, 16 rows ----------------

__global__ __launch_bounds__(64) void k_emb(const float* __restrict__ x, const unsigned short* __restrict__ wfT,
                                            const float* __restrict__ bf_,
                                            float* __restrict__ x_emb, float* __restrict__ accb) {
    int lane = threadIdx.x & 63;
    int l16 = lane & 15, quad = lane >> 4;
    int m0 = blockIdx.x * 16;
    const float* xrow = x + (size_t)(m0 + l16) * IN_DIM + quad * 8;
    f32x4 acc[8];
#pragma unroll
    for (int nt = 0; nt < 8; ++nt) acc[nt] = (f32x4){0.f, 0.f, 0.f, 0.f};
#pragma unroll
    for (int kt = 0; kt < IN_DIM / 32; ++kt) {
        float4 p = *reinterpret_cast<const float4*>(xrow + kt * 32);
        float4 q = *reinterpret_cast<const float4*>(xrow + kt * 32 + 4);
        bf16x8 a = cvt8(p, q);
#pragma unroll
        for (int nt = 0; nt < 8; ++nt) {
            bf16x8 b = *reinterpret_cast<const bf16x8*>(&wfT[(size_t)(nt * 16 + l16) * IN_DIM + kt * 32 + quad * 8]);
            acc[nt] = __builtin_amdgcn_mfma_f32_16x16x32_bf16(a, b, acc[nt], 0, 0, 0);
        }
    }
#pragma unroll
    for (int nt = 0; nt < 8; ++nt) {
        int col = nt * 16 + l16;
        float bias = bf_[col];
#pragma unroll
        for (int r = 0; r < 4; ++r) {
            int row = m0 + quad * 4 + r;
            float v = acc[nt][r] + bias;
            size_t o = (size_t)row * HID + col;
            x_emb[o] = v;
            accb[o] = v;
        }
    }
}

// ---------------- one LightGCN layer (unchanged fp32 gather) ----------------

__device__ __forceinline__ void fma4(float4& a, const float4& v, float s) {
    a.x = fmaf(v.x, s, a.x);
    a.y = fmaf(v.y, s, a.y);
    a.z = fmaf(v.z, s, a.z);
    a.w = fmaf(v.w, s, a.w);
}

__global__ __launch_bounds__(128) void k_prop(const float* __restrict__ cur, float* __restrict__ nxt,
                                              float* __restrict__ accb,
                                              const int* __restrict__ row_start,
                                              const int* __restrict__ csr_src, const float* __restrict__ csr_w) {
    int tid = threadIdx.x;
    int n = blockIdx.x * 4 + (tid >> 5);
    int c4 = (tid & 31) * 4;
    int s = row_start[n];
    int e = row_start[n + 1];
    float4 a0 = {0.f, 0.f, 0.f, 0.f}, a1 = a0, a2 = a0, a3 = a0;
    int i = s;
    for (; i + 4 <= e; i += 4) {
        int s0 = csr_src[i], s1 = csr_src[i + 1], s2 = csr_src[i + 2], s3 = csr_src[i + 3];
        float w0 = csr_w[i], w1 = csr_w[i + 1], w2 = csr_w[i + 2], w3 = csr_w[i + 3];
        float4 v0 = *reinterpret_cast<const float4*>(&cur[(size_t)s0 * HID + c4]);
        float4 v1 = *reinterpret_cast<const float4*>(&cur[(size_t)s1 * HID + c4]);
        float4 v2 = *reinterpret_cast<const float4*>(&cur[(size_t)s2 * HID + c4]);
        float4 v3 = *reinterpret_cast<const float4*>(&cur[(size_t)s3 * HID + c4]);
        fma4(a0, v0, w0); fma4(a1, v1, w1); fma4(a2, v2, w2); fma4(a3, v3, w3);
    }
    for (; i < e; ++i) {
        int s0 = csr_src[i];
        float w0 = csr_w[i];
        float4 v0 = *reinterpret_cast<const float4*>(&cur[(size_t)s0 * HID + c4]);
        fma4(a0, v0, w0);
    }
    a0.x += a1.x + a2.x + a3.x;
    a0.y += a1.y + a2.y + a3.y;
    a0.z += a1.z + a2.z + a3.z;
    a0.w += a1.w + a2.w + a3.w;
    size_t o = (size_t)n * HID + c4;
    *reinterpret_cast<float4*>(&nxt[o]) = a0;
    float4 ac = *reinterpret_cast<const float4*>(&accb[o]);
    ac.x += a0.x; ac.y += a0.y; ac.z += a0.z; ac.w += a0.w;
    *reinterpret_cast<float4*>(&accb[o]) = ac;
}

// ---------------- Hm = softmax((x_emb @ w_hyper + g)/tau) : MFMA, 1 wave/block ----------------

__global__ __launch_bounds__(64) void k_soft(const float* __restrict__ x_emb, const unsigned short* __restrict__ whT,
                                             const float* __restrict__ gu, float* __restrict__ Hm) {
    int lane = threadIdx.x & 63;
    int l16 = lane & 15, quad = lane >> 4;
    int m0 = blockIdx.x * 16;
    const float* xrow = x_emb + (size_t)(m0 + l16) * HID + quad * 8;
    f32x4 acc[16];
#pragma unroll
    for (int nt = 0; nt < 16; ++nt) acc[nt] = (f32x4){0.f, 0.f, 0.f, 0.f};
#pragma unroll
    for (int kt = 0; kt < HID / 32; ++kt) {
        float4 p = *reinterpret_cast<const float4*>(xrow + kt * 32);
        float4 q = *reinterpret_cast<const float4*>(xrow + kt * 32 + 4);
        bf16x8 a = cvt8(p, q);
#pragma unroll
        for (int nt = 0; nt < 16; ++nt) {
            bf16x8 b = *reinterpret_cast<const bf16x8*>(&whT[(size_t)(nt * 16 + l16) * HID + kt * 32 + quad * 8]);
            acc[nt] = __builtin_amdgcn_mfma_f32_16x16x32_bf16(a, b, acc[nt], 0, 0, 0);
        }
    }
    // gumbel + 1/tau
#pragma unroll
    for (int nt = 0; nt < 16; ++nt) {
        int col = nt * 16 + l16;
#pragma unroll
        for (int r = 0; r < 4; ++r) {
            int row = m0 + quad * 4 + r;
            float u = gu[(size_t)row * HYP + col];
            float g = -logf(-logf(u + 1e-10f) + 1e-10f);
            acc[nt][r] = (acc[nt][r] + g) * 2.0f;
        }
    }
    // row max / sum over cols: per-lane over nt, then shfl over lane&15 group
    float mx[4] = {-3.4e38f, -3.4e38f, -3.4e38f, -3.4e38f};
#pragma unroll
    for (int nt = 0; nt < 16; ++nt)
#pragma unroll
        for (int r = 0; r < 4; ++r) mx[r] = fmaxf(mx[r], acc[nt][r]);
#pragma unroll
    for (int r = 0; r < 4; ++r) {
        mx[r] = fmaxf(mx[r], __shfl_xor(mx[r], 1));
        mx[r] = fmaxf(mx[r], __shfl_xor(mx[r], 2));
        mx[r] = fmaxf(mx[r], __shfl_xor(mx[r], 4));
        mx[r] = fmaxf(mx[r], __shfl_xor(mx[r], 8));
    }
    float sm[4] = {0.f, 0.f, 0.f, 0.f};
#pragma unroll
    for (int nt = 0; nt < 16; ++nt)
#pragma unroll
        for (int r = 0; r < 4; ++r) {
            float e = __expf(acc[nt][r] - mx[r]);
            acc[nt][r] = e;
            sm[r] += e;
        }
#pragma unroll
    for (int r = 0; r < 4; ++r) {
        sm[r] += __shfl_xor(sm[r], 1);
        sm[r] += __shfl_xor(sm[r], 2);
        sm[r] += __shfl_xor(sm[r], 4);
        sm[r] += __shfl_xor(sm[r], 8);
        sm[r] = 1.0f / sm[r];
    }
#pragma unroll
    for (int nt = 0; nt < 16; ++nt) {
        int col = nt * 16 + l16;
#pragma unroll
        for (int r = 0; r < 4; ++r)
            Hm[(size_t)(m0 + quad * 4 + r) * HYP + col] = acc[nt][r] * sm[r];
    }
}

// ---------------- lat = Hm^T @ x_emb : register-tiled outer product, split-K, ATOMIC-FREE ----------------
// grid = 2 * LAT_KC blocks; bx&1 selects h-half (128 of 256), bx>>1 selects K-chunk.
// Each thread owns an 8h x 8d accumulator; per node: 4 float4 loads + 64 FMAs, no LDS, no syncs.
// Epilogue: plain float4 stores of the block's 128x128 partial tile to part[bx] (NO atomics —
// round-1 showed 12.6M contended fp32 atomics = 400 MB HBM write traffic, 90% of kernel time).
// Blocks with an empty K-chunk still write their (zero) tile so the reduction is uniform.

#define LAT_KC 384

__global__ __launch_bounds__(256) void k_lat(const float* __restrict__ Hm, const float* __restrict__ x_emb,
                                             float* __restrict__ part) {
    int htile = blockIdx.x & 1;
    int kc = blockIdx.x >> 1;
    const int chunk = (N_NODES + LAT_KC - 1) / LAT_KC;  // 131
    int start = kc * chunk;
    int end = min(N_NODES, start + chunk);
    int nn = end - start;  // may be <= 0 for the last couple of chunks
    int tid = threadIdx.x;
    int lh = (tid & 15) * 8;               // 8 consecutive h (within half) per thread
    int d = (tid >> 4) * 8;                // 8 consecutive d per thread
    const float* __restrict__ hp = Hm + (size_t)start * HYP + htile * 128 + lh;
    const float* __restrict__ xp = x_emb + (size_t)start * HID + d;
    float acc[8][8];
#pragma unroll
    for (int i = 0; i < 8; ++i)
#pragma unroll
        for (int j = 0; j < 8; ++j) acc[i][j] = 0.f;
#pragma unroll 2
    for (int n = 0; n < nn; ++n) {
        float4 a0 = *reinterpret_cast<const float4*>(hp);
        float4 a1 = *reinterpret_cast<const float4*>(hp + 4);
        float4 b0 = *reinterpret_cast<const float4*>(xp);
        float4 b1 = *reinterpret_cast<const float4*>(xp + 4);
        float av[8] = {a0.x, a0.y, a0.z, a0.w, a1.x, a1.y, a1.z, a1.w};
        float bv[8] = {b0.x, b0.y, b0.z, b0.w, b1.x, b1.y, b1.z, b1.w};
#pragma unroll
        for (int i = 0; i < 8; ++i)
#pragma unroll
            for (int j = 0; j < 8; ++j) acc[i][j] = fmaf(av[i], bv[j], acc[i][j]);
        hp += HYP;
        xp += HID;
    }
    float* __restrict__ pp = part + (size_t)blockIdx.x * (128 * 128) + (size_t)lh * 128 + d;
#pragma unroll
    for (int i = 0; i < 8; ++i) {
        float4 v0 = {acc[i][0], acc[i][1], acc[i][2], acc[i][3]};
        float4 v1 = {acc[i][4], acc[i][5], acc[i][6], acc[i][7]};
        *reinterpret_cast<float4*>(pp + i * 128) = v0;
        *reinterpret_cast<float4*>(pp + i * 128 + 4) = v1;
    }
}

// ---------------- reduce split-K partials -> latT (bf16, transposed) directly ----------------
// 32768 output elements (h in [0,256), d in [0,128)); one thread each; coalesced reads
// (a wave reads 64 consecutive d for fixed h,k). Writes latT[d][h] (128 KB, L2-resident).

__global__ __launch_bounds__(256) void k_lat_red(const float* __restrict__ part, unsigned short* __restrict__ latT) {
    int idx = blockIdx.x * 256 + threadIdx.x;  // [0, 32768)
    int d = idx & 127;
    int h = idx >> 7;
    int htile = h >> 7;
    int lh = h & 127;
    const float* __restrict__ p0 = part + (size_t)htile * (128 * 128) + (size_t)lh * 128 + d;
    const size_t kstride = (size_t)2 * 128 * 128;  // consecutive kc
    float s0 = 0.f, s1 = 0.f, s2 = 0.f, s3 = 0.f;
#pragma unroll 4
    for (int k = 0; k < LAT_KC; k += 4) {
        s0 += p0[(size_t)k * kstride];
        s1 += p0[(size_t)(k + 1) * kstride];
        s2 += p0[(size_t)(k + 2) * kstride];
        s3 += p0[(size_t)(k + 3) * kstride];
    }
    latT[(size_t)d * HYP + h] = f2bf((s0 + s1) + (s2 + s3));
}

// ---------------- tail: hyper = Hm @ lat; norm; final; two head GEMMs — MFMA, 1 wave/block ----------------

__global__ __launch_bounds__(64) void k_tail(const float* __restrict__ Hm, const unsigned short* __restrict__ latT,
                                             const float* __restrict__ accb,
                                             const unsigned short* __restrict__ wvT, const float* __restrict__ bv,
                                             const unsigned short* __restrict__ wtT, const float* __restrict__ bt,
                                             float* __restrict__ out_final, float* __restrict__ out_vis,
                                             float* __restrict__ out_txt) {
    __shared__ unsigned short fl[16 * HID];  // final tile, bf16, 4 KB
    int lane = threadIdx.x & 63;
    int l16 = lane & 15, quad = lane >> 4;
    int m0 = blockIdx.x * 16;
    const float* hrow = Hm + (size_t)(m0 + l16) * HYP + quad * 8;
    f32x4 acc[8];
#pragma unroll
    for (int nt = 0; nt < 8; ++nt) acc[nt] = (f32x4){0.f, 0.f, 0.f, 0.f};
#pragma unroll
    for (int kt = 0; kt < HYP / 32; ++kt) {
        float4 p = *reinterpret_cast<const float4*>(hrow + kt * 32);
        float4 q = *reinterpret_cast<const float4*>(hrow + kt * 32 + 4);
        bf16x8 a = cvt8(p, q);
#pragma unroll
        for (int nt = 0; nt < 8; ++nt) {
            bf16x8 b = *reinterpret_cast<const bf16x8*>(&latT[(size_t)(nt * 16 + l16) * HYP + kt * 32 + quad * 8]);
            acc[nt] = __builtin_amdgcn_mfma_f32_16x16x32_bf16(a, b, acc[nt], 0, 0, 0);
        }
    }
    // per-row L2 norm: rows = m0 + quad*4 + r; reduce over cols = nt x (lane&15)
    float ss[4] = {0.f, 0.f, 0.f, 0.f};
#pragma unroll
    for (int nt = 0; nt < 8; ++nt)
#pragma unroll
        for (int r = 0; r < 4; ++r) ss[r] = fmaf(acc[nt][r], acc[nt][r], ss[r]);
#pragma unroll
    for (int r = 0; r < 4; ++r) {
        ss[r] += __shfl_xor(ss[r], 1);
        ss[r] += __shfl_xor(ss[r], 2);
        ss[r] += __shfl_xor(ss[r], 4);
        ss[r] += __shfl_xor(ss[r], 8);
        ss[r] = 1.0f / fmaxf(sqrtf(ss[r]), 1e-12f);
    }
    // final = accb/4 + 0.1 * normalized; store + stage bf16 tile for head GEMMs
#pragma unroll
    for (int nt = 0; nt < 8; ++nt) {
        int col = nt * 16 + l16;
#pragma unroll
        for (int r = 0; r < 4; ++r) {
            int lrow = quad * 4 + r;
            size_t o = (size_t)(m0 + lrow) * HID + col;
            float f = accb[o] * 0.25f + 0.1f * (acc[nt][r] * ss[r]);
            out_final[o] = f;
            fl[lrow * HID + col] = f2bf(f);
        }
    }
    __syncthreads();
    // heads: A = final tile (LDS), B = wvT / wtT
    f32x4 av[8], at4[8];
#pragma unroll
    for (int nt = 0; nt < 8; ++nt) {
        av[nt] = (f32x4){0.f, 0.f, 0.f, 0.f};
        at4[nt] = (f32x4){0.f, 0.f, 0.f, 0.f};
    }
#pragma unroll
    for (int kt = 0; kt < HID / 32; ++kt) {
        bf16x8 a = *reinterpret_cast<const bf16x8*>(&fl[l16 * HID + kt * 32 + quad * 8]);
#pragma unroll
        for (int nt = 0; nt < 8; ++nt) {
            bf16x8 b1 = *reinterpret_cast<const bf16x8*>(&wvT[(size_t)(nt * 16 + l16) * HID + kt * 32 + quad * 8]);
            bf16x8 b2 = *reinterpret_cast<const bf16x8*>(&wtT[(size_t)(nt * 16 + l16) * HID + kt * 32 + quad * 8]);
            av[nt] = __builtin_amdgcn_mfma_f32_16x16x32_bf16(a, b1, av[nt], 0, 0, 0);
            at4[nt] = __builtin_amdgcn_mfma_f32_16x16x32_bf16(a, b2, at4[nt], 0, 0, 0);
        }
    }
#pragma unroll
    for (int nt = 0; nt < 8; ++nt) {
        int col = nt * 16 + l16;
        float b1 = bv[col], b2 = bt[col];
#pragma unroll
        for (int r = 0; r < 4; ++r) {
            size_t o = (size_t)(m0 + quad * 4 + r) * HID + col;
            out_vis[o] = fmaxf(av[nt][r] + b1, 0.0f);
            out_txt[o] = fmaxf(at4[nt][r] + b2, 0.0f);
        }
    }
}

// ---------------- launch ----------------

extern "C" void kernel_launch(void* const* d_in, const int* in_sizes, int n_in,
                              void* d_out, int out_size, void* d_ws, size_t ws_size,
                              hipStream_t stream) {
    const float* x      = (const float*)d_in[0];
    const int*   ei     = (const int*)d_in[1];
    const float* gu     = (const float*)d_in[2];
    const float* w_feat = (const float*)d_in[3];
    const float* b_feat = (const float*)d_in[4];
    const float* w_hyp  = (const float*)d_in[5];
    const float* w_vis  = (const float*)d_in[6];
    const float* b_vis  = (const float*)d_in[7];
    const float* w_txt  = (const float*)d_in[8];
    const float* b_txt  = (const float*)d_in[9];
    float* out = (float*)d_out;

    const int* srcv = ei;
    const int* dstv = ei + E_EDGES;

    char* p = (char*)d_ws;
    int*   deg     = (int*)p;   p += (size_t)N_NODES * 4;
    int*   cnt     = (int*)p;   p += (size_t)N_NODES * 4;
    float* lat     = (float*)p; p += (size_t)HYP * HID * 4;  // kept for layout stability (unused)
    int*   rs      = (int*)p;   p += (size_t)(N_NODES + 1) * 4;
    float* dinv    = (float*)p; p += (size_t)N_NODES * 4;
    int*   csr_src = (int*)p;   p += (size_t)E_EDGES * 4;
    float* csr_w   = (float*)p; p += (size_t)E_EDGES * 4;
    float* x_emb   = (float*)p; p += (size_t)N_NODES * HID * 4;
    float* bufA    = (float*)p; p += (size_t)N_NODES * HID * 4;
    float* bufB    = (float*)p; p += (size_t)N_NODES * HID * 4;
    float* accb    = (float*)p; p += (size_t)N_NODES * HID * 4;
    float* Hm      = (float*)p; p += (size_t)N_NODES * HYP * 4;
    unsigned short* wfT  = (unsigned short*)p; p += (size_t)HID * IN_DIM * 2;  // [128][384]
    unsigned short* whT  = (unsigned short*)p; p += (size_t)HYP * HID * 2;     // [256][128]
    unsigned short* wvT  = (unsigned short*)p; p += (size_t)HID * HID * 2;     // [128][128]
    unsigned short* wtT  = (unsigned short*)p; p += (size_t)HID * HID * 2;     // [128][128]
    unsigned short* latT = (unsigned short*)p; p += (size_t)HID * HYP * 2;     // [128][256]

    // split-K partials for k_lat: 768 tiles x 64 KB = 50.33 MB.
    // bufA+bufB are contiguous (51.2 MB) and dead after the k_prop chain (their data is
    // folded into accb inside k_prop), so reuse them — no extra workspace needed.
    float* latPart = bufA;

    // zero: deg, cnt, lat (contiguous at the head of ws)
    (void)hipMemsetAsync(d_ws, 0, (size_t)(2 * N_NODES + HYP * HID) * 4, stream);

    // weight transposes/converts (independent of graph work)
    k_cvtT<<<(IN_DIM * HID + 255) / 256, 256, 0, stream>>>(w_feat, wfT, IN_DIM, HID);
    k_cvtT<<<(HID * HYP + 255) / 256, 256, 0, stream>>>(w_hyp, whT, HID, HYP);
    k_cvtT<<<(HID * HID + 255) / 256, 256, 0, stream>>>(w_vis, wvT, HID, HID);
    k_cvtT<<<(HID * HID + 255) / 256, 256, 0, stream>>>(w_txt, wtT, HID, HID);

    k_deg<<<(E_EDGES + 255) / 256, 256, 0, stream>>>(dstv, deg);
    k_scan<<<1, 1024, 0, stream>>>(deg, rs, dinv);
    k_fill<<<(E_EDGES + 255) / 256, 256, 0, stream>>>(srcv, dstv, rs, cnt, dinv, csr_src, csr_w);

    k_emb<<<N_NODES / 16, 64, 0, stream>>>(x, wfT, b_feat, x_emb, accb);
    k_prop<<<N_NODES / 4, 128, 0, stream>>>(x_emb, bufA, accb, rs, csr_src, csr_w);
    k_prop<<<N_NODES / 4, 128, 0, stream>>>(bufA, bufB, accb, rs, csr_src, csr_w);
    k_prop<<<N_NODES / 4, 128, 0, stream>>>(bufB, bufA, accb, rs, csr_src, csr_w);
    k_soft<<<N_NODES / 16, 64, 0, stream>>>(x_emb, whT, gu, Hm);
    k_lat<<<2 * LAT_KC, 256, 0, stream>>>(Hm, x_emb, latPart);
    k_lat_red<<<(HYP * HID) / 256, 256, 0, stream>>>(latPart, latT);
    k_tail<<<N_NODES / 16, 64, 0, stream>>>(Hm, latT, accb, wvT, b_vis, wtT, b_txt,
                                            out, out + (size_t)N_NODES * HID, out + (size_t)2 * N_NODES * HID);
}

// Round 3
// 705.539 us; speedup vs baseline: 1.6302x; 1.1346x over previous
//
#include <hip/hip_runtime.h>
#include <math.h>

#define N_NODES 50000
#define E_EDGES 600000
#define IN_DIM  384
#define HID     128
#define HYP     256

#define SCAN_NB ((N_NODES + 255) / 256)  // 196

typedef __attribute__((ext_vector_type(8))) short bf16x8;
typedef __attribute__((ext_vector_type(4))) float f32x4;

__device__ __forceinline__ unsigned short f2bf(float f) {
    unsigned u = __builtin_bit_cast(unsigned, f);
    u = (u + 0x7FFFu + ((u >> 16) & 1u)) >> 16;
    return (unsigned short)u;
}

__device__ __forceinline__ bf16x8 cvt8(float4 p, float4 q) {
    bf16x8 a;
    a[0] = (short)f2bf(p.x); a[1] = (short)f2bf(p.y);
    a[2] = (short)f2bf(p.z); a[3] = (short)f2bf(p.w);
    a[4] = (short)f2bf(q.x); a[5] = (short)f2bf(q.y);
    a[6] = (short)f2bf(q.z); a[7] = (short)f2bf(q.w);
    return a;
}

// ---------------- graph preprocessing ----------------

__global__ void k_deg(const int* __restrict__ dst, int* __restrict__ deg) {
    int i = blockIdx.x * blockDim.x + threadIdx.x;
    if (i < E_EDGES) atomicAdd(&deg[dst[i]], 1);
}

// hierarchical scan, phase 1: per-block (256 elems) sum of deg -> bsum
__global__ __launch_bounds__(256) void k_scan1(const int* __restrict__ deg, int* __restrict__ bsum) {
    __shared__ int sh[256];
    int tid = threadIdx.x;
    int i = blockIdx.x * 256 + tid;
    sh[tid] = (i < N_NODES) ? deg[i] : 0;
    __syncthreads();
#pragma unroll
    for (int off = 128; off > 0; off >>= 1) {
        if (tid < off) sh[tid] += sh[tid + off];
        __syncthreads();
    }
    if (tid == 0) bsum[blockIdx.x] = sh[0];
}

// phase 2: single block scans the 196 block sums -> exclusive bbase
__global__ __launch_bounds__(256) void k_scan2(const int* __restrict__ bsum, int* __restrict__ bbase,
                                               int* __restrict__ row_start) {
    __shared__ int sh[256];
    int tid = threadIdx.x;
    int v = (tid < SCAN_NB) ? bsum[tid] : 0;
    sh[tid] = v;
    __syncthreads();
#pragma unroll
    for (int off = 1; off < 256; off <<= 1) {
        int t = (tid >= off) ? sh[tid - off] : 0;
        __syncthreads();
        sh[tid] += t;
        __syncthreads();
    }
    if (tid < SCAN_NB) bbase[tid] = sh[tid] - v;  // exclusive prefix of block sums
    if (tid == 0) row_start[N_NODES] = E_EDGES;
}

// phase 3: in-block exclusive scan + bbase -> row_start, dinv (coalesced)
__global__ __launch_bounds__(256) void k_scan3(const int* __restrict__ deg, const int* __restrict__ bbase,
                                               int* __restrict__ row_start, float* __restrict__ dinv) {
    __shared__ int sh[256];
    int tid = threadIdx.x;
    int i = blockIdx.x * 256 + tid;
    int d = (i < N_NODES) ? deg[i] : 0;
    sh[tid] = d;
    __syncthreads();
#pragma unroll
    for (int off = 1; off < 256; off <<= 1) {
        int t = (tid >= off) ? sh[tid - off] : 0;
        __syncthreads();
        sh[tid] += t;
        __syncthreads();
    }
    if (i < N_NODES) {
        row_start[i] = sh[tid] - d + bbase[blockIdx.x];
        dinv[i] = (d > 0) ? rsqrtf((float)d) : 0.0f;
    }
}

__global__ void k_fill(const int* __restrict__ src, const int* __restrict__ dst,
                       const int* __restrict__ row_start, int* __restrict__ cnt,
                       const float* __restrict__ dinv,
                       int* __restrict__ csr_src, float* __restrict__ csr_w) {
    int i = blockIdx.x * blockDim.x + threadIdx.x;
    if (i < E_EDGES) {
        int d = dst[i], s = src[i];
        int pos = row_start[d] + atomicAdd(&cnt[d], 1);
        csr_src[pos] = s;
        csr_w[pos] = dinv[s] * dinv[d];
    }
}

// ---------------- transpose + fp32->bf16 convert: out[c][r] = bf16(in[r][c]) ----------------

__global__ void k_cvtT(const float* __restrict__ in, unsigned short* __restrict__ out, int R, int C) {
    int i = blockIdx.x * 256 + threadIdx.x;
    if (i < R * C) {
        int r = i / C;
        int c = i - r * C;
        out[(size_t)c * R + r] = f2bf(in[i]);
    }
}

// ---------------- x_emb = x @ w_feat + b : MFMA, 1 wave/block, 16 rows ----------------

__global__ __launch_bounds__(64) void k_emb(const float* __restrict__ x, const unsigned short* __restrict__ wfT,
                                            const float* __restrict__ bf_,
                                            float* __restrict__ x_emb, float* __restrict__ accb) {
    int lane = threadIdx.x & 63;
    int l16 = lane & 15, quad = lane >> 4;
    int m0 = blockIdx.x * 16;
    const float* xrow = x + (size_t)(m0 + l16) * IN_DIM + quad * 8;
    f32x4 acc[8];
#pragma unroll
    for (int nt = 0; nt < 8; ++nt) acc[nt] = (f32x4){0.f, 0.f, 0.f, 0.f};
#pragma unroll
    for (int kt = 0; kt < IN_DIM / 32; ++kt) {
        float4 p = *reinterpret_cast<const float4*>(xrow + kt * 32);
        float4 q = *reinterpret_cast<const float4*>(xrow + kt * 32 + 4);
        bf16x8 a = cvt8(p, q);
#pragma unroll
        for (int nt = 0; nt < 8; ++nt) {
            bf16x8 b = *reinterpret_cast<const bf16x8*>(&wfT[(size_t)(nt * 16 + l16) * IN_DIM + kt * 32 + quad * 8]);
            acc[nt] = __builtin_amdgcn_mfma_f32_16x16x32_bf16(a, b, acc[nt], 0, 0, 0);
        }
    }
#pragma unroll
    for (int nt = 0; nt < 8; ++nt) {
        int col = nt * 16 + l16;
        float bias = bf_[col];
#pragma unroll
        for (int r = 0; r < 4; ++r) {
            int row = m0 + quad * 4 + r;
            float v = acc[nt][r] + bias;
            size_t o = (size_t)row * HID + col;
            x_emb[o] = v;
            accb[o] = v;
        }
    }
}

// ---------------- one LightGCN layer (unchanged fp32 gather) ----------------

__device__ __forceinline__ void fma4(float4& a, const float4& v, float s) {
    a.x = fmaf(v.x, s, a.x);
    a.y = fmaf(v.y, s, a.y);
    a.z = fmaf(v.z, s, a.z);
    a.w = fmaf(v.w, s, a.w);
}

__global__ __launch_bounds__(128) void k_prop(const float* __restrict__ cur, float* __restrict__ nxt,
                                              float* __restrict__ accb,
                                              const int* __restrict__ row_start,
                                              const int* __restrict__ csr_src, const float* __restrict__ csr_w) {
    int tid = threadIdx.x;
    int n = blockIdx.x * 4 + (tid >> 5);
    int c4 = (tid & 31) * 4;
    int s = row_start[n];
    int e = row_start[n + 1];
    float4 a0 = {0.f, 0.f, 0.f, 0.f}, a1 = a0, a2 = a0, a3 = a0;
    int i = s;
    for (; i + 4 <= e; i += 4) {
        int s0 = csr_src[i], s1 = csr_src[i + 1], s2 = csr_src[i + 2], s3 = csr_src[i + 3];
        float w0 = csr_w[i], w1 = csr_w[i + 1], w2 = csr_w[i + 2], w3 = csr_w[i + 3];
        float4 v0 = *reinterpret_cast<const float4*>(&cur[(size_t)s0 * HID + c4]);
        float4 v1 = *reinterpret_cast<const float4*>(&cur[(size_t)s1 * HID + c4]);
        float4 v2 = *reinterpret_cast<const float4*>(&cur[(size_t)s2 * HID + c4]);
        float4 v3 = *reinterpret_cast<const float4*>(&cur[(size_t)s3 * HID + c4]);
        fma4(a0, v0, w0); fma4(a1, v1, w1); fma4(a2, v2, w2); fma4(a3, v3, w3);
    }
    for (; i < e; ++i) {
        int s0 = csr_src[i];
        float w0 = csr_w[i];
        float4 v0 = *reinterpret_cast<const float4*>(&cur[(size_t)s0 * HID + c4]);
        fma4(a0, v0, w0);
    }
    a0.x += a1.x + a2.x + a3.x;
    a0.y += a1.y + a2.y + a3.y;
    a0.z += a1.z + a2.z + a3.z;
    a0.w += a1.w + a2.w + a3.w;
    size_t o = (size_t)n * HID + c4;
    *reinterpret_cast<float4*>(&nxt[o]) = a0;
    float4 ac = *reinterpret_cast<const float4*>(&accb[o]);
    ac.x += a0.x; ac.y += a0.y; ac.z += a0.z; ac.w += a0.w;
    *reinterpret_cast<float4*>(&accb[o]) = ac;
}

// ---------------- Hm = softmax((x_emb @ w_hyper + g)/tau) : MFMA, 1 wave/block ----------------

__global__ __launch_bounds__(64) void k_soft(const float* __restrict__ x_emb, const unsigned short* __restrict__ whT,
                                             const float* __restrict__ gu, float* __restrict__ Hm) {
    int lane = threadIdx.x & 63;
    int l16 = lane & 15, quad = lane >> 4;
    int m0 = blockIdx.x * 16;
    const float* xrow = x_emb + (size_t)(m0 + l16) * HID + quad * 8;
    f32x4 acc[16];
#pragma unroll
    for (int nt = 0; nt < 16; ++nt) acc[nt] = (f32x4){0.f, 0.f, 0.f, 0.f};
#pragma unroll
    for (int kt = 0; kt < HID / 32; ++kt) {
        float4 p = *reinterpret_cast<const float4*>(xrow + kt * 32);
        float4 q = *reinterpret_cast<const float4*>(xrow + kt * 32 + 4);
        bf16x8 a = cvt8(p, q);
#pragma unroll
        for (int nt = 0; nt < 16; ++nt) {
            bf16x8 b = *reinterpret_cast<const bf16x8*>(&whT[(size_t)(nt * 16 + l16) * HID + kt * 32 + quad * 8]);
            acc[nt] = __builtin_amdgcn_mfma_f32_16x16x32_bf16(a, b, acc[nt], 0, 0, 0);
        }
    }
    // gumbel + 1/tau
#pragma unroll
    for (int nt = 0; nt < 16; ++nt) {
        int col = nt * 16 + l16;
#pragma unroll
        for (int r = 0; r < 4; ++r) {
            int row = m0 + quad * 4 + r;
            float u = gu[(size_t)row * HYP + col];
            float g = -logf(-logf(u + 1e-10f) + 1e-10f);
            acc[nt][r] = (acc[nt][r] + g) * 2.0f;
        }
    }
    // row max / sum over cols: per-lane over nt, then shfl over lane&15 group
    float mx[4] = {-3.4e38f, -3.4e38f, -3.4e38f, -3.4e38f};
#pragma unroll
    for (int nt = 0; nt < 16; ++nt)
#pragma unroll
        for (int r = 0; r < 4; ++r) mx[r] = fmaxf(mx[r], acc[nt][r]);
#pragma unroll
    for (int r = 0; r < 4; ++r) {
        mx[r] = fmaxf(mx[r], __shfl_xor(mx[r], 1));
        mx[r] = fmaxf(mx[r], __shfl_xor(mx[r], 2));
        mx[r] = fmaxf(mx[r], __shfl_xor(mx[r], 4));
        mx[r] = fmaxf(mx[r], __shfl_xor(mx[r], 8));
    }
    float sm[4] = {0.f, 0.f, 0.f, 0.f};
#pragma unroll
    for (int nt = 0; nt < 16; ++nt)
#pragma unroll
        for (int r = 0; r < 4; ++r) {
            float e = __expf(acc[nt][r] - mx[r]);
            acc[nt][r] = e;
            sm[r] += e;
        }
#pragma unroll
    for (int r = 0; r < 4; ++r) {
        sm[r] += __shfl_xor(sm[r], 1);
        sm[r] += __shfl_xor(sm[r], 2);
        sm[r] += __shfl_xor(sm[r], 4);
        sm[r] += __shfl_xor(sm[r], 8);
        sm[r] = 1.0f / sm[r];
    }
#pragma unroll
    for (int nt = 0; nt < 16; ++nt) {
        int col = nt * 16 + l16;
#pragma unroll
        for (int r = 0; r < 4; ++r)
            Hm[(size_t)(m0 + quad * 4 + r) * HYP + col] = acc[nt][r] * sm[r];
    }
}

// ---------------- lat = Hm^T @ x_emb : register-tiled outer product, split-K, ATOMIC-FREE ----------------

#define LAT_KC 384

__global__ __launch_bounds__(256) void k_lat(const float* __restrict__ Hm, const float* __restrict__ x_emb,
                                             float* __restrict__ part) {
    int htile = blockIdx.x & 1;
    int kc = blockIdx.x >> 1;
    const int chunk = (N_NODES + LAT_KC - 1) / LAT_KC;  // 131
    int start = kc * chunk;
    int end = min(N_NODES, start + chunk);
    int nn = end - start;  // may be <= 0 for the last couple of chunks
    int tid = threadIdx.x;
    int lh = (tid & 15) * 8;               // 8 consecutive h (within half) per thread
    int d = (tid >> 4) * 8;                // 8 consecutive d per thread
    const float* __restrict__ hp = Hm + (size_t)start * HYP + htile * 128 + lh;
    const float* __restrict__ xp = x_emb + (size_t)start * HID + d;
    float acc[8][8];
#pragma unroll
    for (int i = 0; i < 8; ++i)
#pragma unroll
        for (int j = 0; j < 8; ++j) acc[i][j] = 0.f;
#pragma unroll 2
    for (int n = 0; n < nn; ++n) {
        float4 a0 = *reinterpret_cast<const float4*>(hp);
        float4 a1 = *reinterpret_cast<const float4*>(hp + 4);
        float4 b0 = *reinterpret_cast<const float4*>(xp);
        float4 b1 = *reinterpret_cast<const float4*>(xp + 4);
        float av[8] = {a0.x, a0.y, a0.z, a0.w, a1.x, a1.y, a1.z, a1.w};
        float bv[8] = {b0.x, b0.y, b0.z, b0.w, b1.x, b1.y, b1.z, b1.w};
#pragma unroll
        for (int i = 0; i < 8; ++i)
#pragma unroll
            for (int j = 0; j < 8; ++j) acc[i][j] = fmaf(av[i], bv[j], acc[i][j]);
        hp += HYP;
        xp += HID;
    }
    float* __restrict__ pp = part + (size_t)blockIdx.x * (128 * 128) + (size_t)lh * 128 + d;
#pragma unroll
    for (int i = 0; i < 8; ++i) {
        float4 v0 = {acc[i][0], acc[i][1], acc[i][2], acc[i][3]};
        float4 v1 = {acc[i][4], acc[i][5], acc[i][6], acc[i][7]};
        *reinterpret_cast<float4*>(pp + i * 128) = v0;
        *reinterpret_cast<float4*>(pp + i * 128 + 4) = v1;
    }
}

// ---------------- reduce split-K partials -> latT (bf16, transposed) directly ----------------

__global__ __launch_bounds__(256) void k_lat_red(const float* __restrict__ part, unsigned short* __restrict__ latT) {
    int idx = blockIdx.x * 256 + threadIdx.x;  // [0, 32768)
    int d = idx & 127;
    int h = idx >> 7;
    int htile = h >> 7;
    int lh = h & 127;
    const float* __restrict__ p0 = part + (size_t)htile * (128 * 128) + (size_t)lh * 128 + d;
    const size_t kstride = (size_t)2 * 128 * 128;  // consecutive kc
    float s0 = 0.f, s1 = 0.f, s2 = 0.f, s3 = 0.f;
#pragma unroll 4
    for (int k = 0; k < LAT_KC; k += 4) {
        s0 += p0[(size_t)k * kstride];
        s1 += p0[(size_t)(k + 1) * kstride];
        s2 += p0[(size_t)(k + 2) * kstride];
        s3 += p0[(size_t)(k + 3) * kstride];
    }
    latT[(size_t)d * HYP + h] = f2bf((s0 + s1) + (s2 + s3));
}

// ---------------- tail: hyper = Hm @ lat; norm; final; two head GEMMs — MFMA, 1 wave/block ----------------

__global__ __launch_bounds__(64) void k_tail(const float* __restrict__ Hm, const unsigned short* __restrict__ latT,
                                             const float* __restrict__ accb,
                                             const unsigned short* __restrict__ wvT, const float* __restrict__ bv,
                                             const unsigned short* __restrict__ wtT, const float* __restrict__ bt,
                                             float* __restrict__ out_final, float* __restrict__ out_vis,
                                             float* __restrict__ out_txt) {
    __shared__ unsigned short fl[16 * HID];  // final tile, bf16, 4 KB
    int lane = threadIdx.x & 63;
    int l16 = lane & 15, quad = lane >> 4;
    int m0 = blockIdx.x * 16;
    const float* hrow = Hm + (size_t)(m0 + l16) * HYP + quad * 8;
    f32x4 acc[8];
#pragma unroll
    for (int nt = 0; nt < 8; ++nt) acc[nt] = (f32x4){0.f, 0.f, 0.f, 0.f};
#pragma unroll
    for (int kt = 0; kt < HYP / 32; ++kt) {
        float4 p = *reinterpret_cast<const float4*>(hrow + kt * 32);
        float4 q = *reinterpret_cast<const float4*>(hrow + kt * 32 + 4);
        bf16x8 a = cvt8(p, q);
#pragma unroll
        for (int nt = 0; nt < 8; ++nt) {
            bf16x8 b = *reinterpret_cast<const bf16x8*>(&latT[(size_t)(nt * 16 + l16) * HYP + kt * 32 + quad * 8]);
            acc[nt] = __builtin_amdgcn_mfma_f32_16x16x32_bf16(a, b, acc[nt], 0, 0, 0);
        }
    }
    // per-row L2 norm: rows = m0 + quad*4 + r; reduce over cols = nt x (lane&15)
    float ss[4] = {0.f, 0.f, 0.f, 0.f};
#pragma unroll
    for (int nt = 0; nt < 8; ++nt)
#pragma unroll
        for (int r = 0; r < 4; ++r) ss[r] = fmaf(acc[nt][r], acc[nt][r], ss[r]);
#pragma unroll
    for (int r = 0; r < 4; ++r) {
        ss[r] += __shfl_xor(ss[r], 1);
        ss[r] += __shfl_xor(ss[r], 2);
        ss[r] += __shfl_xor(ss[r], 4);
        ss[r] += __shfl_xor(ss[r], 8);
        ss[r] = 1.0f / fmaxf(sqrtf(ss[r]), 1e-12f);
    }
    // final = accb/4 + 0.1 * normalized; store + stage bf16 tile for head GEMMs
#pragma unroll
    for (int nt = 0; nt < 8; ++nt) {
        int col = nt * 16 + l16;
#pragma unroll
        for (int r = 0; r < 4; ++r) {
            int lrow = quad * 4 + r;
            size_t o = (size_t)(m0 + lrow) * HID + col;
            float f = accb[o] * 0.25f + 0.1f * (acc[nt][r] * ss[r]);
            out_final[o] = f;
            fl[lrow * HID + col] = f2bf(f);
        }
    }
    __syncthreads();
    // heads: A = final tile (LDS), B = wvT / wtT
    f32x4 av[8], at4[8];
#pragma unroll
    for (int nt = 0; nt < 8; ++nt) {
        av[nt] = (f32x4){0.f, 0.f, 0.f, 0.f};
        at4[nt] = (f32x4){0.f, 0.f, 0.f, 0.f};
    }
#pragma unroll
    for (int kt = 0; kt < HID / 32; ++kt) {
        bf16x8 a = *reinterpret_cast<const bf16x8*>(&fl[l16 * HID + kt * 32 + quad * 8]);
#pragma unroll
        for (int nt = 0; nt < 8; ++nt) {
            bf16x8 b1 = *reinterpret_cast<const bf16x8*>(&wvT[(size_t)(nt * 16 + l16) * HID + kt * 32 + quad * 8]);
            bf16x8 b2 = *reinterpret_cast<const bf16x8*>(&wtT[(size_t)(nt * 16 + l16) * HID + kt * 32 + quad * 8]);
            av[nt] = __builtin_amdgcn_mfma_f32_16x16x32_bf16(a, b1, av[nt], 0, 0, 0);
            at4[nt] = __builtin_amdgcn_mfma_f32_16x16x32_bf16(a, b2, at4[nt], 0, 0, 0);
        }
    }
#pragma unroll
    for (int nt = 0; nt < 8; ++nt) {
        int col = nt * 16 + l16;
        float b1 = bv[col], b2 = bt[col];
#pragma unroll
        for (int r = 0; r < 4; ++r) {
            size_t o = (size_t)(m0 + quad * 4 + r) * HID + col;
            out_vis[o] = fmaxf(av[nt][r] + b1, 0.0f);
            out_txt[o] = fmaxf(at4[nt][r] + b2, 0.0f);
        }
    }
}

// ---------------- launch ----------------

extern "C" void kernel_launch(void* const* d_in, const int* in_sizes, int n_in,
                              void* d_out, int out_size, void* d_ws, size_t ws_size,
                              hipStream_t stream) {
    const float* x      = (const float*)d_in[0];
    const int*   ei     = (const int*)d_in[1];
    const float* gu     = (const float*)d_in[2];
    const float* w_feat = (const float*)d_in[3];
    const float* b_feat = (const float*)d_in[4];
    const float* w_hyp  = (const float*)d_in[5];
    const float* w_vis  = (const float*)d_in[6];
    const float* b_vis  = (const float*)d_in[7];
    const float* w_txt  = (const float*)d_in[8];
    const float* b_txt  = (const float*)d_in[9];
    float* out = (float*)d_out;

    const int* srcv = ei;
    const int* dstv = ei + E_EDGES;

    char* p = (char*)d_ws;
    int*   deg     = (int*)p;   p += (size_t)N_NODES * 4;
    int*   cnt     = (int*)p;   p += (size_t)N_NODES * 4;
    float* lat     = (float*)p; p += (size_t)HYP * HID * 4;  // kept for layout stability (unused)
    int*   rs      = (int*)p;   p += (size_t)(N_NODES + 1) * 4;
    float* dinv    = (float*)p; p += (size_t)N_NODES * 4;
    int*   csr_src = (int*)p;   p += (size_t)E_EDGES * 4;
    float* csr_w   = (float*)p; p += (size_t)E_EDGES * 4;
    float* x_emb   = (float*)p; p += (size_t)N_NODES * HID * 4;
    float* bufA    = (float*)p; p += (size_t)N_NODES * HID * 4;
    float* bufB    = (float*)p; p += (size_t)N_NODES * HID * 4;
    float* accb    = (float*)p; p += (size_t)N_NODES * HID * 4;
    float* Hm      = (float*)p; p += (size_t)N_NODES * HYP * 4;
    unsigned short* wfT  = (unsigned short*)p; p += (size_t)HID * IN_DIM * 2;  // [128][384]
    unsigned short* whT  = (unsigned short*)p; p += (size_t)HYP * HID * 2;     // [256][128]
    unsigned short* wvT  = (unsigned short*)p; p += (size_t)HID * HID * 2;     // [128][128]
    unsigned short* wtT  = (unsigned short*)p; p += (size_t)HID * HID * 2;     // [128][128]
    unsigned short* latT = (unsigned short*)p; p += (size_t)HID * HYP * 2;     // [128][256]
    int*   bsum    = (int*)p;   p += (size_t)SCAN_NB * 4;
    int*   bbase   = (int*)p;   p += (size_t)SCAN_NB * 4;

    // split-K partials for k_lat: 768 tiles x 64 KB = 50.33 MB.
    // bufA+bufB are contiguous (51.2 MB) and dead after the k_prop chain, so reuse them.
    float* latPart = bufA;

    // zero: deg, cnt, lat (contiguous at the head of ws)
    (void)hipMemsetAsync(d_ws, 0, (size_t)(2 * N_NODES + HYP * HID) * 4, stream);

    // weight transposes/converts (independent of graph work)
    k_cvtT<<<(IN_DIM * HID + 255) / 256, 256, 0, stream>>>(w_feat, wfT, IN_DIM, HID);
    k_cvtT<<<(HID * HYP + 255) / 256, 256, 0, stream>>>(w_hyp, whT, HID, HYP);
    k_cvtT<<<(HID * HID + 255) / 256, 256, 0, stream>>>(w_vis, wvT, HID, HID);
    k_cvtT<<<(HID * HID + 255) / 256, 256, 0, stream>>>(w_txt, wtT, HID, HID);

    k_deg<<<(E_EDGES + 255) / 256, 256, 0, stream>>>(dstv, deg);
    k_scan1<<<SCAN_NB, 256, 0, stream>>>(deg, bsum);
    k_scan2<<<1, 256, 0, stream>>>(bsum, bbase, rs);
    k_scan3<<<SCAN_NB, 256, 0, stream>>>(deg, bbase, rs, dinv);
    k_fill<<<(E_EDGES + 255) / 256, 256, 0, stream>>>(srcv, dstv, rs, cnt, dinv, csr_src, csr_w);

    k_emb<<<N_NODES / 16, 64, 0, stream>>>(x, wfT, b_feat, x_emb, accb);
    k_prop<<<N_NODES / 4, 128, 0, stream>>>(x_emb, bufA, accb, rs, csr_src, csr_w);
    k_prop<<<N_NODES / 4, 128, 0, stream>>>(bufA, bufB, accb, rs, csr_src, csr_w);
    k_prop<<<N_NODES / 4, 128, 0, stream>>>(bufB, bufA, accb, rs, csr_src, csr_w);
    k_soft<<<N_NODES / 16, 64, 0, stream>>>(x_emb, whT, gu, Hm);
    k_lat<<<2 * LAT_KC, 256, 0, stream>>>(Hm, x_emb, latPart);
    k_lat_red<<<(HYP * HID) / 256, 256, 0, stream>>>(latPart, latT);
    k_tail<<<N_NODES / 16, 64, 0, stream>>>(Hm, latT, accb, wvT, b_vis, wtT, b_txt,
                                            out, out + (size_t)N_NODES * HID, out + (size_t)2 * N_NODES * HID);
}

// Round 4
// 698.430 us; speedup vs baseline: 1.6468x; 1.0102x over previous
//
#include <hip/hip_runtime.h>
#include <math.h>

#define N_NODES 50000
#define E_EDGES 600000
#define IN_DIM  384
#define HID     128
#define HYP     256

#define SCAN_NB ((N_NODES + 255) / 256)  // 196

typedef __attribute__((ext_vector_type(8))) short bf16x8;
typedef __attribute__((ext_vector_type(4))) float f32x4;

__device__ __forceinline__ unsigned short f2bf(float f) {
    unsigned u = __builtin_bit_cast(unsigned, f);
    u = (u + 0x7FFFu + ((u >> 16) & 1u)) >> 16;
    return (unsigned short)u;
}

__device__ __forceinline__ bf16x8 cvt8(float4 p, float4 q) {
    bf16x8 a;
    a[0] = (short)f2bf(p.x); a[1] = (short)f2bf(p.y);
    a[2] = (short)f2bf(p.z); a[3] = (short)f2bf(p.w);
    a[4] = (short)f2bf(q.x); a[5] = (short)f2bf(q.y);
    a[6] = (short)f2bf(q.z); a[7] = (short)f2bf(q.w);
    return a;
}

// ---------------- graph preprocessing ----------------

__global__ void k_deg(const int* __restrict__ dst, int* __restrict__ deg) {
    int i = blockIdx.x * blockDim.x + threadIdx.x;
    if (i < E_EDGES) atomicAdd(&deg[dst[i]], 1);
}

// hierarchical scan, phase 1: per-block (256 elems) sum of deg -> bsum
__global__ __launch_bounds__(256) void k_scan1(const int* __restrict__ deg, int* __restrict__ bsum) {
    __shared__ int sh[256];
    int tid = threadIdx.x;
    int i = blockIdx.x * 256 + tid;
    sh[tid] = (i < N_NODES) ? deg[i] : 0;
    __syncthreads();
#pragma unroll
    for (int off = 128; off > 0; off >>= 1) {
        if (tid < off) sh[tid] += sh[tid + off];
        __syncthreads();
    }
    if (tid == 0) bsum[blockIdx.x] = sh[0];
}

// phase 2: single block scans the 196 block sums -> exclusive bbase
__global__ __launch_bounds__(256) void k_scan2(const int* __restrict__ bsum, int* __restrict__ bbase,
                                               int* __restrict__ row_start) {
    __shared__ int sh[256];
    int tid = threadIdx.x;
    int v = (tid < SCAN_NB) ? bsum[tid] : 0;
    sh[tid] = v;
    __syncthreads();
#pragma unroll
    for (int off = 1; off < 256; off <<= 1) {
        int t = (tid >= off) ? sh[tid - off] : 0;
        __syncthreads();
        sh[tid] += t;
        __syncthreads();
    }
    if (tid < SCAN_NB) bbase[tid] = sh[tid] - v;  // exclusive prefix of block sums
    if (tid == 0) row_start[N_NODES] = E_EDGES;
}

// phase 3: in-block exclusive scan + bbase -> row_start, dinv (coalesced)
__global__ __launch_bounds__(256) void k_scan3(const int* __restrict__ deg, const int* __restrict__ bbase,
                                               int* __restrict__ row_start, float* __restrict__ dinv) {
    __shared__ int sh[256];
    int tid = threadIdx.x;
    int i = blockIdx.x * 256 + tid;
    int d = (i < N_NODES) ? deg[i] : 0;
    sh[tid] = d;
    __syncthreads();
#pragma unroll
    for (int off = 1; off < 256; off <<= 1) {
        int t = (tid >= off) ? sh[tid - off] : 0;
        __syncthreads();
        sh[tid] += t;
        __syncthreads();
    }
    if (i < N_NODES) {
        row_start[i] = sh[tid] - d + bbase[blockIdx.x];
        dinv[i] = (d > 0) ? rsqrtf((float)d) : 0.0f;
    }
}

__global__ void k_fill(const int* __restrict__ src, const int* __restrict__ dst,
                       const int* __restrict__ row_start, int* __restrict__ cnt,
                       const float* __restrict__ dinv,
                       int* __restrict__ csr_src, float* __restrict__ csr_w) {
    int i = blockIdx.x * blockDim.x + threadIdx.x;
    if (i < E_EDGES) {
        int d = dst[i], s = src[i];
        int pos = row_start[d] + atomicAdd(&cnt[d], 1);
        csr_src[pos] = s;
        csr_w[pos] = dinv[s] * dinv[d];
    }
}

// ---------------- transpose + fp32->bf16 convert: out[c][r] = bf16(in[r][c]) ----------------

__global__ void k_cvtT(const float* __restrict__ in, unsigned short* __restrict__ out, int R, int C) {
    int i = blockIdx.x * 256 + threadIdx.x;
    if (i < R * C) {
        int r = i / C;
        int c = i - r * C;
        out[(size_t)c * R + r] = f2bf(in[i]);
    }
}

// ---------------- x_emb = x @ w_feat + b : MFMA, 2 waves/block split-K, 16 rows ----------------
// Round-3 counters: old 1-wave version was latency-bound (VALUBusy 2.5%, Occ 19.6%,
// only ~2 HBM loads in flight). Now: wave w handles K in [w*192, w*192+192); all 12
// x-row float4 loads issued upfront (12 outstanding HBM loads/wave); LDS reduce; only
// x_emb written (accb init folded into the first k_prop).

__global__ __launch_bounds__(128) void k_emb(const float* __restrict__ x, const unsigned short* __restrict__ wfT,
                                             const float* __restrict__ bf_, float* __restrict__ x_emb) {
    __shared__ float red[16 * HID];  // 8 KB
    int tid = threadIdx.x;
    int wid = tid >> 6;            // K-half
    int lane = tid & 63;
    int l16 = lane & 15, quad = lane >> 4;
    int m0 = blockIdx.x * 16;
    const float* xrow = x + (size_t)(m0 + l16) * IN_DIM + wid * 192 + quad * 8;
    // preload the wave's entire K-half of its 16 rows: 6 kt x 2 float4 per lane
    float4 P[6], Q[6];
#pragma unroll
    for (int kt = 0; kt < 6; ++kt) {
        P[kt] = *reinterpret_cast<const float4*>(xrow + kt * 32);
        Q[kt] = *reinterpret_cast<const float4*>(xrow + kt * 32 + 4);
    }
    f32x4 acc[8];
#pragma unroll
    for (int nt = 0; nt < 8; ++nt) acc[nt] = (f32x4){0.f, 0.f, 0.f, 0.f};
#pragma unroll
    for (int kt = 0; kt < 6; ++kt) {
        bf16x8 a = cvt8(P[kt], Q[kt]);
#pragma unroll
        for (int nt = 0; nt < 8; ++nt) {
            bf16x8 b = *reinterpret_cast<const bf16x8*>(
                &wfT[(size_t)(nt * 16 + l16) * IN_DIM + wid * 192 + kt * 32 + quad * 8]);
            acc[nt] = __builtin_amdgcn_mfma_f32_16x16x32_bf16(a, b, acc[nt], 0, 0, 0);
        }
    }
    // cross-wave reduce: wave1 stages partial, wave0 adds + bias + store
    if (wid == 1) {
#pragma unroll
        for (int nt = 0; nt < 8; ++nt)
#pragma unroll
            for (int r = 0; r < 4; ++r)
                red[(quad * 4 + r) * HID + nt * 16 + l16] = acc[nt][r];
    }
    __syncthreads();
    if (wid == 0) {
#pragma unroll
        for (int nt = 0; nt < 8; ++nt) {
            int col = nt * 16 + l16;
            float bias = bf_[col];
#pragma unroll
            for (int r = 0; r < 4; ++r) {
                int lrow = quad * 4 + r;
                float v = acc[nt][r] + red[lrow * HID + col] + bias;
                x_emb[(size_t)(m0 + lrow) * HID + col] = v;
            }
        }
    }
}

// ---------------- one LightGCN layer (fp32 gather) ----------------
// INIT=1 (first layer): accb = cur[n] + a0   (cur == x_emb; replaces k_emb's accb store)
// INIT=0:               accb += a0

__device__ __forceinline__ void fma4(float4& a, const float4& v, float s) {
    a.x = fmaf(v.x, s, a.x);
    a.y = fmaf(v.y, s, a.y);
    a.z = fmaf(v.z, s, a.z);
    a.w = fmaf(v.w, s, a.w);
}

template <int INIT>
__global__ __launch_bounds__(128) void k_prop(const float* __restrict__ cur, float* __restrict__ nxt,
                                              float* __restrict__ accb,
                                              const int* __restrict__ row_start,
                                              const int* __restrict__ csr_src, const float* __restrict__ csr_w) {
    int tid = threadIdx.x;
    int n = blockIdx.x * 4 + (tid >> 5);
    int c4 = (tid & 31) * 4;
    int s = row_start[n];
    int e = row_start[n + 1];
    float4 a0 = {0.f, 0.f, 0.f, 0.f}, a1 = a0, a2 = a0, a3 = a0;
    int i = s;
    for (; i + 4 <= e; i += 4) {
        int s0 = csr_src[i], s1 = csr_src[i + 1], s2 = csr_src[i + 2], s3 = csr_src[i + 3];
        float w0 = csr_w[i], w1 = csr_w[i + 1], w2 = csr_w[i + 2], w3 = csr_w[i + 3];
        float4 v0 = *reinterpret_cast<const float4*>(&cur[(size_t)s0 * HID + c4]);
        float4 v1 = *reinterpret_cast<const float4*>(&cur[(size_t)s1 * HID + c4]);
        float4 v2 = *reinterpret_cast<const float4*>(&cur[(size_t)s2 * HID + c4]);
        float4 v3 = *reinterpret_cast<const float4*>(&cur[(size_t)s3 * HID + c4]);
        fma4(a0, v0, w0); fma4(a1, v1, w1); fma4(a2, v2, w2); fma4(a3, v3, w3);
    }
    for (; i < e; ++i) {
        int s0 = csr_src[i];
        float w0 = csr_w[i];
        float4 v0 = *reinterpret_cast<const float4*>(&cur[(size_t)s0 * HID + c4]);
        fma4(a0, v0, w0);
    }
    a0.x += a1.x + a2.x + a3.x;
    a0.y += a1.y + a2.y + a3.y;
    a0.z += a1.z + a2.z + a3.z;
    a0.w += a1.w + a2.w + a3.w;
    size_t o = (size_t)n * HID + c4;
    *reinterpret_cast<float4*>(&nxt[o]) = a0;
    float4 ac;
    if (INIT) ac = *reinterpret_cast<const float4*>(&cur[o]);
    else      ac = *reinterpret_cast<const float4*>(&accb[o]);
    ac.x += a0.x; ac.y += a0.y; ac.z += a0.z; ac.w += a0.w;
    *reinterpret_cast<float4*>(&accb[o]) = ac;
}

// ---------------- Hm = softmax((x_emb @ w_hyper + g)/tau) : MFMA, 1 wave/block ----------------

__global__ __launch_bounds__(64) void k_soft(const float* __restrict__ x_emb, const unsigned short* __restrict__ whT,
                                             const float* __restrict__ gu, float* __restrict__ Hm) {
    int lane = threadIdx.x & 63;
    int l16 = lane & 15, quad = lane >> 4;
    int m0 = blockIdx.x * 16;
    const float* xrow = x_emb + (size_t)(m0 + l16) * HID + quad * 8;
    f32x4 acc[16];
#pragma unroll
    for (int nt = 0; nt < 16; ++nt) acc[nt] = (f32x4){0.f, 0.f, 0.f, 0.f};
#pragma unroll
    for (int kt = 0; kt < HID / 32; ++kt) {
        float4 p = *reinterpret_cast<const float4*>(xrow + kt * 32);
        float4 q = *reinterpret_cast<const float4*>(xrow + kt * 32 + 4);
        bf16x8 a = cvt8(p, q);
#pragma unroll
        for (int nt = 0; nt < 16; ++nt) {
            bf16x8 b = *reinterpret_cast<const bf16x8*>(&whT[(size_t)(nt * 16 + l16) * HID + kt * 32 + quad * 8]);
            acc[nt] = __builtin_amdgcn_mfma_f32_16x16x32_bf16(a, b, acc[nt], 0, 0, 0);
        }
    }
    // gumbel + 1/tau
#pragma unroll
    for (int nt = 0; nt < 16; ++nt) {
        int col = nt * 16 + l16;
#pragma unroll
        for (int r = 0; r < 4; ++r) {
            int row = m0 + quad * 4 + r;
            float u = gu[(size_t)row * HYP + col];
            float g = -logf(-logf(u + 1e-10f) + 1e-10f);
            acc[nt][r] = (acc[nt][r] + g) * 2.0f;
        }
    }
    // row max / sum over cols: per-lane over nt, then shfl over lane&15 group
    float mx[4] = {-3.4e38f, -3.4e38f, -3.4e38f, -3.4e38f};
#pragma unroll
    for (int nt = 0; nt < 16; ++nt)
#pragma unroll
        for (int r = 0; r < 4; ++r) mx[r] = fmaxf(mx[r], acc[nt][r]);
#pragma unroll
    for (int r = 0; r < 4; ++r) {
        mx[r] = fmaxf(mx[r], __shfl_xor(mx[r], 1));
        mx[r] = fmaxf(mx[r], __shfl_xor(mx[r], 2));
        mx[r] = fmaxf(mx[r], __shfl_xor(mx[r], 4));
        mx[r] = fmaxf(mx[r], __shfl_xor(mx[r], 8));
    }
    float sm[4] = {0.f, 0.f, 0.f, 0.f};
#pragma unroll
    for (int nt = 0; nt < 16; ++nt)
#pragma unroll
        for (int r = 0; r < 4; ++r) {
            float e = __expf(acc[nt][r] - mx[r]);
            acc[nt][r] = e;
            sm[r] += e;
        }
#pragma unroll
    for (int r = 0; r < 4; ++r) {
        sm[r] += __shfl_xor(sm[r], 1);
        sm[r] += __shfl_xor(sm[r], 2);
        sm[r] += __shfl_xor(sm[r], 4);
        sm[r] += __shfl_xor(sm[r], 8);
        sm[r] = 1.0f / sm[r];
    }
#pragma unroll
    for (int nt = 0; nt < 16; ++nt) {
        int col = nt * 16 + l16;
#pragma unroll
        for (int r = 0; r < 4; ++r)
            Hm[(size_t)(m0 + quad * 4 + r) * HYP + col] = acc[nt][r] * sm[r];
    }
}

// ---------------- lat = Hm^T @ x_emb : register-tiled outer product, split-K, ATOMIC-FREE ----------------

#define LAT_KC 384

__global__ __launch_bounds__(256) void k_lat(const float* __restrict__ Hm, const float* __restrict__ x_emb,
                                             float* __restrict__ part) {
    int htile = blockIdx.x & 1;
    int kc = blockIdx.x >> 1;
    const int chunk = (N_NODES + LAT_KC - 1) / LAT_KC;  // 131
    int start = kc * chunk;
    int end = min(N_NODES, start + chunk);
    int nn = end - start;  // may be <= 0 for the last couple of chunks
    int tid = threadIdx.x;
    int lh = (tid & 15) * 8;               // 8 consecutive h (within half) per thread
    int d = (tid >> 4) * 8;                // 8 consecutive d per thread
    const float* __restrict__ hp = Hm + (size_t)start * HYP + htile * 128 + lh;
    const float* __restrict__ xp = x_emb + (size_t)start * HID + d;
    float acc[8][8];
#pragma unroll
    for (int i = 0; i < 8; ++i)
#pragma unroll
        for (int j = 0; j < 8; ++j) acc[i][j] = 0.f;
#pragma unroll 2
    for (int n = 0; n < nn; ++n) {
        float4 a0 = *reinterpret_cast<const float4*>(hp);
        float4 a1 = *reinterpret_cast<const float4*>(hp + 4);
        float4 b0 = *reinterpret_cast<const float4*>(xp);
        float4 b1 = *reinterpret_cast<const float4*>(xp + 4);
        float av[8] = {a0.x, a0.y, a0.z, a0.w, a1.x, a1.y, a1.z, a1.w};
        float bv[8] = {b0.x, b0.y, b0.z, b0.w, b1.x, b1.y, b1.z, b1.w};
#pragma unroll
        for (int i = 0; i < 8; ++i)
#pragma unroll
            for (int j = 0; j < 8; ++j) acc[i][j] = fmaf(av[i], bv[j], acc[i][j]);
        hp += HYP;
        xp += HID;
    }
    float* __restrict__ pp = part + (size_t)blockIdx.x * (128 * 128) + (size_t)lh * 128 + d;
#pragma unroll
    for (int i = 0; i < 8; ++i) {
        float4 v0 = {acc[i][0], acc[i][1], acc[i][2], acc[i][3]};
        float4 v1 = {acc[i][4], acc[i][5], acc[i][6], acc[i][7]};
        *reinterpret_cast<float4*>(pp + i * 128) = v0;
        *reinterpret_cast<float4*>(pp + i * 128 + 4) = v1;
    }
}

// ---------------- reduce split-K partials -> latT (bf16, transposed) directly ----------------

__global__ __launch_bounds__(256) void k_lat_red(const float* __restrict__ part, unsigned short* __restrict__ latT) {
    int idx = blockIdx.x * 256 + threadIdx.x;  // [0, 32768)
    int d = idx & 127;
    int h = idx >> 7;
    int htile = h >> 7;
    int lh = h & 127;
    const float* __restrict__ p0 = part + (size_t)htile * (128 * 128) + (size_t)lh * 128 + d;
    const size_t kstride = (size_t)2 * 128 * 128;  // consecutive kc
    float s0 = 0.f, s1 = 0.f, s2 = 0.f, s3 = 0.f;
#pragma unroll 4
    for (int k = 0; k < LAT_KC; k += 4) {
        s0 += p0[(size_t)k * kstride];
        s1 += p0[(size_t)(k + 1) * kstride];
        s2 += p0[(size_t)(k + 2) * kstride];
        s3 += p0[(size_t)(k + 3) * kstride];
    }
    latT[(size_t)d * HYP + h] = f2bf((s0 + s1) + (s2 + s3));
}

// ---------------- tail: hyper = Hm @ lat; norm; final; two head GEMMs — MFMA, 1 wave/block ----------------

__global__ __launch_bounds__(64) void k_tail(const float* __restrict__ Hm, const unsigned short* __restrict__ latT,
                                             const float* __restrict__ accb,
                                             const unsigned short* __restrict__ wvT, const float* __restrict__ bv,
                                             const unsigned short* __restrict__ wtT, const float* __restrict__ bt,
                                             float* __restrict__ out_final, float* __restrict__ out_vis,
                                             float* __restrict__ out_txt) {
    __shared__ unsigned short fl[16 * HID];  // final tile, bf16, 4 KB
    int lane = threadIdx.x & 63;
    int l16 = lane & 15, quad = lane >> 4;
    int m0 = blockIdx.x * 16;
    const float* hrow = Hm + (size_t)(m0 + l16) * HYP + quad * 8;
    f32x4 acc[8];
#pragma unroll
    for (int nt = 0; nt < 8; ++nt) acc[nt] = (f32x4){0.f, 0.f, 0.f, 0.f};
#pragma unroll
    for (int kt = 0; kt < HYP / 32; ++kt) {
        float4 p = *reinterpret_cast<const float4*>(hrow + kt * 32);
        float4 q = *reinterpret_cast<const float4*>(hrow + kt * 32 + 4);
        bf16x8 a = cvt8(p, q);
#pragma unroll
        for (int nt = 0; nt < 8; ++nt) {
            bf16x8 b = *reinterpret_cast<const bf16x8*>(&latT[(size_t)(nt * 16 + l16) * HYP + kt * 32 + quad * 8]);
            acc[nt] = __builtin_amdgcn_mfma_f32_16x16x32_bf16(a, b, acc[nt], 0, 0, 0);
        }
    }
    // per-row L2 norm: rows = m0 + quad*4 + r; reduce over cols = nt x (lane&15)
    float ss[4] = {0.f, 0.f, 0.f, 0.f};
#pragma unroll
    for (int nt = 0; nt < 8; ++nt)
#pragma unroll
        for (int r = 0; r < 4; ++r) ss[r] = fmaf(acc[nt][r], acc[nt][r], ss[r]);
#pragma unroll
    for (int r = 0; r < 4; ++r) {
        ss[r] += __shfl_xor(ss[r], 1);
        ss[r] += __shfl_xor(ss[r], 2);
        ss[r] += __shfl_xor(ss[r], 4);
        ss[r] += __shfl_xor(ss[r], 8);
        ss[r] = 1.0f / fmaxf(sqrtf(ss[r]), 1e-12f);
    }
    // final = accb/4 + 0.1 * normalized; store + stage bf16 tile for head GEMMs
#pragma unroll
    for (int nt = 0; nt < 8; ++nt) {
        int col = nt * 16 + l16;
#pragma unroll
        for (int r = 0; r < 4; ++r) {
            int lrow = quad * 4 + r;
            size_t o = (size_t)(m0 + lrow) * HID + col;
            float f = accb[o] * 0.25f + 0.1f * (acc[nt][r] * ss[r]);
            out_final[o] = f;
            fl[lrow * HID + col] = f2bf(f);
        }
    }
    __syncthreads();
    // heads: A = final tile (LDS), B = wvT / wtT
    f32x4 av[8], at4[8];
#pragma unroll
    for (int nt = 0; nt < 8; ++nt) {
        av[nt] = (f32x4){0.f, 0.f, 0.f, 0.f};
        at4[nt] = (f32x4){0.f, 0.f, 0.f, 0.f};
    }
#pragma unroll
    for (int kt = 0; kt < HID / 32; ++kt) {
        bf16x8 a = *reinterpret_cast<const bf16x8*>(&fl[l16 * HID + kt * 32 + quad * 8]);
#pragma unroll
        for (int nt = 0; nt < 8; ++nt) {
            bf16x8 b1 = *reinterpret_cast<const bf16x8*>(&wvT[(size_t)(nt * 16 + l16) * HID + kt * 32 + quad * 8]);
            bf16x8 b2 = *reinterpret_cast<const bf16x8*>(&wtT[(size_t)(nt * 16 + l16) * HID + kt * 32 + quad * 8]);
            av[nt] = __builtin_amdgcn_mfma_f32_16x16x32_bf16(a, b1, av[nt], 0, 0, 0);
            at4[nt] = __builtin_amdgcn_mfma_f32_16x16x32_bf16(a, b2, at4[nt], 0, 0, 0);
        }
    }
#pragma unroll
    for (int nt = 0; nt < 8; ++nt) {
        int col = nt * 16 + l16;
        float b1 = bv[col], b2 = bt[col];
#pragma unroll
        for (int r = 0; r < 4; ++r) {
            size_t o = (size_t)(m0 + quad * 4 + r) * HID + col;
            out_vis[o] = fmaxf(av[nt][r] + b1, 0.0f);
            out_txt[o] = fmaxf(at4[nt][r] + b2, 0.0f);
        }
    }
}

// ---------------- launch ----------------

extern "C" void kernel_launch(void* const* d_in, const int* in_sizes, int n_in,
                              void* d_out, int out_size, void* d_ws, size_t ws_size,
                              hipStream_t stream) {
    const float* x      = (const float*)d_in[0];
    const int*   ei     = (const int*)d_in[1];
    const float* gu     = (const float*)d_in[2];
    const float* w_feat = (const float*)d_in[3];
    const float* b_feat = (const float*)d_in[4];
    const float* w_hyp  = (const float*)d_in[5];
    const float* w_vis  = (const float*)d_in[6];
    const float* b_vis  = (const float*)d_in[7];
    const float* w_txt  = (const float*)d_in[8];
    const float* b_txt  = (const float*)d_in[9];
    float* out = (float*)d_out;

    const int* srcv = ei;
    const int* dstv = ei + E_EDGES;

    char* p = (char*)d_ws;
    int*   deg     = (int*)p;   p += (size_t)N_NODES * 4;
    int*   cnt     = (int*)p;   p += (size_t)N_NODES * 4;
    float* lat     = (float*)p; p += (size_t)HYP * HID * 4;  // kept for layout stability (unused)
    int*   rs      = (int*)p;   p += (size_t)(N_NODES + 1) * 4;
    float* dinv    = (float*)p; p += (size_t)N_NODES * 4;
    int*   csr_src = (int*)p;   p += (size_t)E_EDGES * 4;
    float* csr_w   = (float*)p; p += (size_t)E_EDGES * 4;
    float* x_emb   = (float*)p; p += (size_t)N_NODES * HID * 4;
    float* bufA    = (float*)p; p += (size_t)N_NODES * HID * 4;
    float* bufB    = (float*)p; p += (size_t)N_NODES * HID * 4;
    float* accb    = (float*)p; p += (size_t)N_NODES * HID * 4;
    float* Hm      = (float*)p; p += (size_t)N_NODES * HYP * 4;
    unsigned short* wfT  = (unsigned short*)p; p += (size_t)HID * IN_DIM * 2;  // [128][384]
    unsigned short* whT  = (unsigned short*)p; p += (size_t)HYP * HID * 2;     // [256][128]
    unsigned short* wvT  = (unsigned short*)p; p += (size_t)HID * HID * 2;     // [128][128]
    unsigned short* wtT  = (unsigned short*)p; p += (size_t)HID * HID * 2;     // [128][128]
    unsigned short* latT = (unsigned short*)p; p += (size_t)HID * HYP * 2;     // [128][256]
    int*   bsum    = (int*)p;   p += (size_t)SCAN_NB * 4;
    int*   bbase   = (int*)p;   p += (size_t)SCAN_NB * 4;

    // split-K partials for k_lat: 768 tiles x 64 KB = 50.33 MB.
    // bufA+bufB are contiguous (51.2 MB) and dead after the k_prop chain, so reuse them.
    float* latPart = bufA;

    // zero: deg, cnt, lat (contiguous at the head of ws)
    (void)hipMemsetAsync(d_ws, 0, (size_t)(2 * N_NODES + HYP * HID) * 4, stream);

    // weight transposes/converts (independent of graph work)
    k_cvtT<<<(IN_DIM * HID + 255) / 256, 256, 0, stream>>>(w_feat, wfT, IN_DIM, HID);
    k_cvtT<<<(HID * HYP + 255) / 256, 256, 0, stream>>>(w_hyp, whT, HID, HYP);
    k_cvtT<<<(HID * HID + 255) / 256, 256, 0, stream>>>(w_vis, wvT, HID, HID);
    k_cvtT<<<(HID * HID + 255) / 256, 256, 0, stream>>>(w_txt, wtT, HID, HID);

    k_deg<<<(E_EDGES + 255) / 256, 256, 0, stream>>>(dstv, deg);
    k_scan1<<<SCAN_NB, 256, 0, stream>>>(deg, bsum);
    k_scan2<<<1, 256, 0, stream>>>(bsum, bbase, rs);
    k_scan3<<<SCAN_NB, 256, 0, stream>>>(deg, bbase, rs, dinv);
    k_fill<<<(E_EDGES + 255) / 256, 256, 0, stream>>>(srcv, dstv, rs, cnt, dinv, csr_src, csr_w);

    k_emb<<<N_NODES / 16, 128, 0, stream>>>(x, wfT, b_feat, x_emb);
    k_prop<1><<<N_NODES / 4, 128, 0, stream>>>(x_emb, bufA, accb, rs, csr_src, csr_w);
    k_prop<0><<<N_NODES / 4, 128, 0, stream>>>(bufA, bufB, accb, rs, csr_src, csr_w);
    k_prop<0><<<N_NODES / 4, 128, 0, stream>>>(bufB, bufA, accb, rs, csr_src, csr_w);
    k_soft<<<N_NODES / 16, 64, 0, stream>>>(x_emb, whT, gu, Hm);
    k_lat<<<2 * LAT_KC, 256, 0, stream>>>(Hm, x_emb, latPart);
    k_lat_red<<<(HYP * HID) / 256, 256, 0, stream>>>(latPart, latT);
    k_tail<<<N_NODES / 16, 64, 0, stream>>>(Hm, latT, accb, wvT, b_vis, wtT, b_txt,
                                            out, out + (size_t)N_NODES * HID, out + (size_t)2 * N_NODES * HID);
}

// Round 5
// 697.091 us; speedup vs baseline: 1.6499x; 1.0019x over previous
//
#include <hip/hip_runtime.h>
#include <math.h>

#define N_NODES 50000
#define E_EDGES 600000
#define IN_DIM  384
#define HID     128
#define HYP     256

#define SCAN_NB ((N_NODES + 255) / 256)  // 196

typedef __attribute__((ext_vector_type(8))) short bf16x8;
typedef __attribute__((ext_vector_type(4))) float f32x4;

__device__ __forceinline__ unsigned short f2bf(float f) {
    unsigned u = __builtin_bit_cast(unsigned, f);
    u = (u + 0x7FFFu + ((u >> 16) & 1u)) >> 16;
    return (unsigned short)u;
}

__device__ __forceinline__ bf16x8 cvt8(float4 p, float4 q) {
    bf16x8 a;
    a[0] = (short)f2bf(p.x); a[1] = (short)f2bf(p.y);
    a[2] = (short)f2bf(p.z); a[3] = (short)f2bf(p.w);
    a[4] = (short)f2bf(q.x); a[5] = (short)f2bf(q.y);
    a[6] = (short)f2bf(q.z); a[7] = (short)f2bf(q.w);
    return a;
}

// ---------------- graph preprocessing ----------------

__global__ void k_deg(const int* __restrict__ dst, int* __restrict__ deg) {
    int i = blockIdx.x * blockDim.x + threadIdx.x;
    if (i < E_EDGES) atomicAdd(&deg[dst[i]], 1);
}

// hierarchical scan, phase 1: per-block (256 elems) sum of deg -> bsum
__global__ __launch_bounds__(256) void k_scan1(const int* __restrict__ deg, int* __restrict__ bsum) {
    __shared__ int sh[256];
    int tid = threadIdx.x;
    int i = blockIdx.x * 256 + tid;
    sh[tid] = (i < N_NODES) ? deg[i] : 0;
    __syncthreads();
#pragma unroll
    for (int off = 128; off > 0; off >>= 1) {
        if (tid < off) sh[tid] += sh[tid + off];
        __syncthreads();
    }
    if (tid == 0) bsum[blockIdx.x] = sh[0];
}

// phase 2: single block scans the 196 block sums -> exclusive bbase
__global__ __launch_bounds__(256) void k_scan2(const int* __restrict__ bsum, int* __restrict__ bbase,
                                               int* __restrict__ row_start) {
    __shared__ int sh[256];
    int tid = threadIdx.x;
    int v = (tid < SCAN_NB) ? bsum[tid] : 0;
    sh[tid] = v;
    __syncthreads();
#pragma unroll
    for (int off = 1; off < 256; off <<= 1) {
        int t = (tid >= off) ? sh[tid - off] : 0;
        __syncthreads();
        sh[tid] += t;
        __syncthreads();
    }
    if (tid < SCAN_NB) bbase[tid] = sh[tid] - v;  // exclusive prefix of block sums
    if (tid == 0) row_start[N_NODES] = E_EDGES;
}

// phase 3: in-block exclusive scan + bbase -> row_start, dinv (coalesced)
__global__ __launch_bounds__(256) void k_scan3(const int* __restrict__ deg, const int* __restrict__ bbase,
                                               int* __restrict__ row_start, float* __restrict__ dinv) {
    __shared__ int sh[256];
    int tid = threadIdx.x;
    int i = blockIdx.x * 256 + tid;
    int d = (i < N_NODES) ? deg[i] : 0;
    sh[tid] = d;
    __syncthreads();
#pragma unroll
    for (int off = 1; off < 256; off <<= 1) {
        int t = (tid >= off) ? sh[tid - off] : 0;
        __syncthreads();
        sh[tid] += t;
        __syncthreads();
    }
    if (i < N_NODES) {
        row_start[i] = sh[tid] - d + bbase[blockIdx.x];
        dinv[i] = (d > 0) ? rsqrtf((float)d) : 0.0f;
    }
}

// fill CSR with interleaved (src, weight) pairs -> one 8B load per edge in k_prop
__global__ void k_fill(const int* __restrict__ src, const int* __restrict__ dst,
                       const int* __restrict__ row_start, int* __restrict__ cnt,
                       const float* __restrict__ dinv, int2* __restrict__ csr_sw) {
    int i = blockIdx.x * blockDim.x + threadIdx.x;
    if (i < E_EDGES) {
        int d = dst[i], s = src[i];
        int pos = row_start[d] + atomicAdd(&cnt[d], 1);
        csr_sw[pos] = make_int2(s, __float_as_int(dinv[s] * dinv[d]));
    }
}

// ---------------- fused weight transpose + fp32->bf16 (was 4 k_cvtT launches) ----------------
// segments: wf 384x128 (49152) | wh 128x256 (32768) | wv 128x128 (16384) | wt 128x128 (16384)
// total 114688 = 448 * 256 exactly.

__global__ __launch_bounds__(256) void k_cvt_all(const float* __restrict__ wf, const float* __restrict__ wh,
                                                 const float* __restrict__ wv, const float* __restrict__ wt,
                                                 unsigned short* __restrict__ wfT, unsigned short* __restrict__ whT,
                                                 unsigned short* __restrict__ wvT, unsigned short* __restrict__ wtT) {
    int i = blockIdx.x * 256 + threadIdx.x;
    if (i < 49152) {
        int r = i >> 7, c = i & 127;                       // in [384][128]
        wfT[(size_t)c * IN_DIM + r] = f2bf(wf[i]);
    } else if (i < 49152 + 32768) {
        int j = i - 49152;
        int r = j >> 8, c = j & 255;                       // in [128][256]
        whT[(size_t)c * HID + r] = f2bf(wh[j]);
    } else if (i < 49152 + 32768 + 16384) {
        int j = i - 81920;
        int r = j >> 7, c = j & 127;                       // in [128][128]
        wvT[(size_t)c * HID + r] = f2bf(wv[j]);
    } else {
        int j = i - 98304;
        int r = j >> 7, c = j & 127;
        wtT[(size_t)c * HID + r] = f2bf(wt[j]);
    }
}

// ---------------- x_emb = x @ w_feat + b : MFMA, 2 waves/block split-K, 16 rows ----------------

__global__ __launch_bounds__(128) void k_emb(const float* __restrict__ x, const unsigned short* __restrict__ wfT,
                                             const float* __restrict__ bf_, float* __restrict__ x_emb) {
    __shared__ float red[16 * HID];  // 8 KB
    int tid = threadIdx.x;
    int wid = tid >> 6;            // K-half
    int lane = tid & 63;
    int l16 = lane & 15, quad = lane >> 4;
    int m0 = blockIdx.x * 16;
    const float* xrow = x + (size_t)(m0 + l16) * IN_DIM + wid * 192 + quad * 8;
    // preload the wave's entire K-half of its 16 rows: 6 kt x 2 float4 per lane
    float4 P[6], Q[6];
#pragma unroll
    for (int kt = 0; kt < 6; ++kt) {
        P[kt] = *reinterpret_cast<const float4*>(xrow + kt * 32);
        Q[kt] = *reinterpret_cast<const float4*>(xrow + kt * 32 + 4);
    }
    f32x4 acc[8];
#pragma unroll
    for (int nt = 0; nt < 8; ++nt) acc[nt] = (f32x4){0.f, 0.f, 0.f, 0.f};
#pragma unroll
    for (int kt = 0; kt < 6; ++kt) {
        bf16x8 a = cvt8(P[kt], Q[kt]);
#pragma unroll
        for (int nt = 0; nt < 8; ++nt) {
            bf16x8 b = *reinterpret_cast<const bf16x8*>(
                &wfT[(size_t)(nt * 16 + l16) * IN_DIM + wid * 192 + kt * 32 + quad * 8]);
            acc[nt] = __builtin_amdgcn_mfma_f32_16x16x32_bf16(a, b, acc[nt], 0, 0, 0);
        }
    }
    // cross-wave reduce: wave1 stages partial, wave0 adds + bias + store
    if (wid == 1) {
#pragma unroll
        for (int nt = 0; nt < 8; ++nt)
#pragma unroll
            for (int r = 0; r < 4; ++r)
                red[(quad * 4 + r) * HID + nt * 16 + l16] = acc[nt][r];
    }
    __syncthreads();
    if (wid == 0) {
#pragma unroll
        for (int nt = 0; nt < 8; ++nt) {
            int col = nt * 16 + l16;
            float bias = bf_[col];
#pragma unroll
            for (int r = 0; r < 4; ++r) {
                int lrow = quad * 4 + r;
                float v = acc[nt][r] + red[lrow * HID + col] + bias;
                x_emb[(size_t)(m0 + lrow) * HID + col] = v;
            }
        }
    }
}

// ---------------- one LightGCN layer: 8-wide masked gather, 8 nodes/block ----------------
// Round-4 theory: latency-bound gather (serial idx->row chain, 4 in flight). Now:
// one int2 (src,w) load per edge, 8 independent row-gathers in flight, padded lanes
// get w=0 (no serial remainder loop).
// INIT=1 (first layer): accb = cur[n] + a   (cur == x_emb)
// INIT=0:               accb += a

__device__ __forceinline__ void fma4(float4& a, const float4& v, float s) {
    a.x = fmaf(v.x, s, a.x);
    a.y = fmaf(v.y, s, a.y);
    a.z = fmaf(v.z, s, a.z);
    a.w = fmaf(v.w, s, a.w);
}

template <int INIT>
__global__ __launch_bounds__(256) void k_prop(const float* __restrict__ cur, float* __restrict__ nxt,
                                              float* __restrict__ accb,
                                              const int* __restrict__ row_start,
                                              const int2* __restrict__ csr_sw) {
    int tid = threadIdx.x;
    int n = blockIdx.x * 8 + (tid >> 5);
    int c4 = (tid & 31) * 4;
    int s = row_start[n];
    int e = row_start[n + 1];
    float4 a[8];
#pragma unroll
    for (int k = 0; k < 8; ++k) a[k] = (float4){0.f, 0.f, 0.f, 0.f};
    for (int i = s; i < e; i += 8) {
        int2 pk[8];
        float wk[8];
#pragma unroll
        for (int k = 0; k < 8; ++k) {
            int j = i + k;
            pk[k] = csr_sw[(j < e) ? j : s];
            wk[k] = (j < e) ? __int_as_float(pk[k].y) : 0.0f;
        }
        float4 v[8];
#pragma unroll
        for (int k = 0; k < 8; ++k)
            v[k] = *reinterpret_cast<const float4*>(&cur[(size_t)pk[k].x * HID + c4]);
#pragma unroll
        for (int k = 0; k < 8; ++k) fma4(a[k], v[k], wk[k]);
    }
    a[0].x += a[1].x; a[0].y += a[1].y; a[0].z += a[1].z; a[0].w += a[1].w;
    a[2].x += a[3].x; a[2].y += a[3].y; a[2].z += a[3].z; a[2].w += a[3].w;
    a[4].x += a[5].x; a[4].y += a[5].y; a[4].z += a[5].z; a[4].w += a[5].w;
    a[6].x += a[7].x; a[6].y += a[7].y; a[6].z += a[7].z; a[6].w += a[7].w;
    a[0].x += a[2].x; a[0].y += a[2].y; a[0].z += a[2].z; a[0].w += a[2].w;
    a[4].x += a[6].x; a[4].y += a[6].y; a[4].z += a[6].z; a[4].w += a[6].w;
    a[0].x += a[4].x; a[0].y += a[4].y; a[0].z += a[4].z; a[0].w += a[4].w;
    size_t o = (size_t)n * HID + c4;
    *reinterpret_cast<float4*>(&nxt[o]) = a[0];
    float4 ac;
    if (INIT) ac = *reinterpret_cast<const float4*>(&cur[o]);
    else      ac = *reinterpret_cast<const float4*>(&accb[o]);
    ac.x += a[0].x; ac.y += a[0].y; ac.z += a[0].z; ac.w += a[0].w;
    *reinterpret_cast<float4*>(&accb[o]) = ac;
}

// ---------------- Hm = softmax((x_emb @ w_hyper + g)/tau) : MFMA, 1 wave/block ----------------

__global__ __launch_bounds__(64) void k_soft(const float* __restrict__ x_emb, const unsigned short* __restrict__ whT,
                                             const float* __restrict__ gu, float* __restrict__ Hm) {
    int lane = threadIdx.x & 63;
    int l16 = lane & 15, quad = lane >> 4;
    int m0 = blockIdx.x * 16;
    const float* xrow = x_emb + (size_t)(m0 + l16) * HID + quad * 8;
    f32x4 acc[16];
#pragma unroll
    for (int nt = 0; nt < 16; ++nt) acc[nt] = (f32x4){0.f, 0.f, 0.f, 0.f};
#pragma unroll
    for (int kt = 0; kt < HID / 32; ++kt) {
        float4 p = *reinterpret_cast<const float4*>(xrow + kt * 32);
        float4 q = *reinterpret_cast<const float4*>(xrow + kt * 32 + 4);
        bf16x8 a = cvt8(p, q);
#pragma unroll
        for (int nt = 0; nt < 16; ++nt) {
            bf16x8 b = *reinterpret_cast<const bf16x8*>(&whT[(size_t)(nt * 16 + l16) * HID + kt * 32 + quad * 8]);
            acc[nt] = __builtin_amdgcn_mfma_f32_16x16x32_bf16(a, b, acc[nt], 0, 0, 0);
        }
    }
    // gumbel + 1/tau
#pragma unroll
    for (int nt = 0; nt < 16; ++nt) {
        int col = nt * 16 + l16;
#pragma unroll
        for (int r = 0; r < 4; ++r) {
            int row = m0 + quad * 4 + r;
            float u = gu[(size_t)row * HYP + col];
            float g = -logf(-logf(u + 1e-10f) + 1e-10f);
            acc[nt][r] = (acc[nt][r] + g) * 2.0f;
        }
    }
    // row max / sum over cols: per-lane over nt, then shfl over lane&15 group
    float mx[4] = {-3.4e38f, -3.4e38f, -3.4e38f, -3.4e38f};
#pragma unroll
    for (int nt = 0; nt < 16; ++nt)
#pragma unroll
        for (int r = 0; r < 4; ++r) mx[r] = fmaxf(mx[r], acc[nt][r]);
#pragma unroll
    for (int r = 0; r < 4; ++r) {
        mx[r] = fmaxf(mx[r], __shfl_xor(mx[r], 1));
        mx[r] = fmaxf(mx[r], __shfl_xor(mx[r], 2));
        mx[r] = fmaxf(mx[r], __shfl_xor(mx[r], 4));
        mx[r] = fmaxf(mx[r], __shfl_xor(mx[r], 8));
    }
    float sm[4] = {0.f, 0.f, 0.f, 0.f};
#pragma unroll
    for (int nt = 0; nt < 16; ++nt)
#pragma unroll
        for (int r = 0; r < 4; ++r) {
            float e = __expf(acc[nt][r] - mx[r]);
            acc[nt][r] = e;
            sm[r] += e;
        }
#pragma unroll
    for (int r = 0; r < 4; ++r) {
        sm[r] += __shfl_xor(sm[r], 1);
        sm[r] += __shfl_xor(sm[r], 2);
        sm[r] += __shfl_xor(sm[r], 4);
        sm[r] += __shfl_xor(sm[r], 8);
        sm[r] = 1.0f / sm[r];
    }
#pragma unroll
    for (int nt = 0; nt < 16; ++nt) {
        int col = nt * 16 + l16;
#pragma unroll
        for (int r = 0; r < 4; ++r)
            Hm[(size_t)(m0 + quad * 4 + r) * HYP + col] = acc[nt][r] * sm[r];
    }
}

// ---------------- lat = Hm^T @ x_emb : register-tiled outer product, split-K, ATOMIC-FREE ----------------

#define LAT_KC 384

__global__ __launch_bounds__(256) void k_lat(const float* __restrict__ Hm, const float* __restrict__ x_emb,
                                             float* __restrict__ part) {
    int htile = blockIdx.x & 1;
    int kc = blockIdx.x >> 1;
    const int chunk = (N_NODES + LAT_KC - 1) / LAT_KC;  // 131
    int start = kc * chunk;
    int end = min(N_NODES, start + chunk);
    int nn = end - start;  // may be <= 0 for the last couple of chunks
    int tid = threadIdx.x;
    int lh = (tid & 15) * 8;               // 8 consecutive h (within half) per thread
    int d = (tid >> 4) * 8;                // 8 consecutive d per thread
    const float* __restrict__ hp = Hm + (size_t)start * HYP + htile * 128 + lh;
    const float* __restrict__ xp = x_emb + (size_t)start * HID + d;
    float acc[8][8];
#pragma unroll
    for (int i = 0; i < 8; ++i)
#pragma unroll
        for (int j = 0; j < 8; ++j) acc[i][j] = 0.f;
#pragma unroll 2
    for (int n = 0; n < nn; ++n) {
        float4 a0 = *reinterpret_cast<const float4*>(hp);
        float4 a1 = *reinterpret_cast<const float4*>(hp + 4);
        float4 b0 = *reinterpret_cast<const float4*>(xp);
        float4 b1 = *reinterpret_cast<const float4*>(xp + 4);
        float av[8] = {a0.x, a0.y, a0.z, a0.w, a1.x, a1.y, a1.z, a1.w};
        float bv[8] = {b0.x, b0.y, b0.z, b0.w, b1.x, b1.y, b1.z, b1.w};
#pragma unroll
        for (int i = 0; i < 8; ++i)
#pragma unroll
            for (int j = 0; j < 8; ++j) acc[i][j] = fmaf(av[i], bv[j], acc[i][j]);
        hp += HYP;
        xp += HID;
    }
    float* __restrict__ pp = part + (size_t)blockIdx.x * (128 * 128) + (size_t)lh * 128 + d;
#pragma unroll
    for (int i = 0; i < 8; ++i) {
        float4 v0 = {acc[i][0], acc[i][1], acc[i][2], acc[i][3]};
        float4 v1 = {acc[i][4], acc[i][5], acc[i][6], acc[i][7]};
        *reinterpret_cast<float4*>(pp + i * 128) = v0;
        *reinterpret_cast<float4*>(pp + i * 128 + 4) = v1;
    }
}

// ---------------- reduce split-K partials -> latT (bf16, transposed) directly ----------------

__global__ __launch_bounds__(256) void k_lat_red(const float* __restrict__ part, unsigned short* __restrict__ latT) {
    int idx = blockIdx.x * 256 + threadIdx.x;  // [0, 32768)
    int d = idx & 127;
    int h = idx >> 7;
    int htile = h >> 7;
    int lh = h & 127;
    const float* __restrict__ p0 = part + (size_t)htile * (128 * 128) + (size_t)lh * 128 + d;
    const size_t kstride = (size_t)2 * 128 * 128;  // consecutive kc
    float s0 = 0.f, s1 = 0.f, s2 = 0.f, s3 = 0.f;
#pragma unroll 4
    for (int k = 0; k < LAT_KC; k += 4) {
        s0 += p0[(size_t)k * kstride];
        s1 += p0[(size_t)(k + 1) * kstride];
        s2 += p0[(size_t)(k + 2) * kstride];
        s3 += p0[(size_t)(k + 3) * kstride];
    }
    latT[(size_t)d * HYP + h] = f2bf((s0 + s1) + (s2 + s3));
}

// ---------------- tail: hyper = Hm @ lat; norm; final; two head GEMMs — MFMA, 1 wave/block ----------------

__global__ __launch_bounds__(64) void k_tail(const float* __restrict__ Hm, const unsigned short* __restrict__ latT,
                                             const float* __restrict__ accb,
                                             const unsigned short* __restrict__ wvT, const float* __restrict__ bv,
                                             const unsigned short* __restrict__ wtT, const float* __restrict__ bt,
                                             float* __restrict__ out_final, float* __restrict__ out_vis,
                                             float* __restrict__ out_txt) {
    __shared__ unsigned short fl[16 * HID];  // final tile, bf16, 4 KB
    int lane = threadIdx.x & 63;
    int l16 = lane & 15, quad = lane >> 4;
    int m0 = blockIdx.x * 16;
    const float* hrow = Hm + (size_t)(m0 + l16) * HYP + quad * 8;
    f32x4 acc[8];
#pragma unroll
    for (int nt = 0; nt < 8; ++nt) acc[nt] = (f32x4){0.f, 0.f, 0.f, 0.f};
#pragma unroll
    for (int kt = 0; kt < HYP / 32; ++kt) {
        float4 p = *reinterpret_cast<const float4*>(hrow + kt * 32);
        float4 q = *reinterpret_cast<const float4*>(hrow + kt * 32 + 4);
        bf16x8 a = cvt8(p, q);
#pragma unroll
        for (int nt = 0; nt < 8; ++nt) {
            bf16x8 b = *reinterpret_cast<const bf16x8*>(&latT[(size_t)(nt * 16 + l16) * HYP + kt * 32 + quad * 8]);
            acc[nt] = __builtin_amdgcn_mfma_f32_16x16x32_bf16(a, b, acc[nt], 0, 0, 0);
        }
    }
    // per-row L2 norm: rows = m0 + quad*4 + r; reduce over cols = nt x (lane&15)
    float ss[4] = {0.f, 0.f, 0.f, 0.f};
#pragma unroll
    for (int nt = 0; nt < 8; ++nt)
#pragma unroll
        for (int r = 0; r < 4; ++r) ss[r] = fmaf(acc[nt][r], acc[nt][r], ss[r]);
#pragma unroll
    for (int r = 0; r < 4; ++r) {
        ss[r] += __shfl_xor(ss[r], 1);
        ss[r] += __shfl_xor(ss[r], 2);
        ss[r] += __shfl_xor(ss[r], 4);
        ss[r] += __shfl_xor(ss[r], 8);
        ss[r] = 1.0f / fmaxf(sqrtf(ss[r]), 1e-12f);
    }
    // final = accb/4 + 0.1 * normalized; store + stage bf16 tile for head GEMMs
#pragma unroll
    for (int nt = 0; nt < 8; ++nt) {
        int col = nt * 16 + l16;
#pragma unroll
        for (int r = 0; r < 4; ++r) {
            int lrow = quad * 4 + r;
            size_t o = (size_t)(m0 + lrow) * HID + col;
            float f = accb[o] * 0.25f + 0.1f * (acc[nt][r] * ss[r]);
            out_final[o] = f;
            fl[lrow * HID + col] = f2bf(f);
        }
    }
    __syncthreads();
    // heads: A = final tile (LDS), B = wvT / wtT
    f32x4 av[8], at4[8];
#pragma unroll
    for (int nt = 0; nt < 8; ++nt) {
        av[nt] = (f32x4){0.f, 0.f, 0.f, 0.f};
        at4[nt] = (f32x4){0.f, 0.f, 0.f, 0.f};
    }
#pragma unroll
    for (int kt = 0; kt < HID / 32; ++kt) {
        bf16x8 a = *reinterpret_cast<const bf16x8*>(&fl[l16 * HID + kt * 32 + quad * 8]);
#pragma unroll
        for (int nt = 0; nt < 8; ++nt) {
            bf16x8 b1 = *reinterpret_cast<const bf16x8*>(&wvT[(size_t)(nt * 16 + l16) * HID + kt * 32 + quad * 8]);
            bf16x8 b2 = *reinterpret_cast<const bf16x8*>(&wtT[(size_t)(nt * 16 + l16) * HID + kt * 32 + quad * 8]);
            av[nt] = __builtin_amdgcn_mfma_f32_16x16x32_bf16(a, b1, av[nt], 0, 0, 0);
            at4[nt] = __builtin_amdgcn_mfma_f32_16x16x32_bf16(a, b2, at4[nt], 0, 0, 0);
        }
    }
#pragma unroll
    for (int nt = 0; nt < 8; ++nt) {
        int col = nt * 16 + l16;
        float b1 = bv[col], b2 = bt[col];
#pragma unroll
        for (int r = 0; r < 4; ++r) {
            size_t o = (size_t)(m0 + quad * 4 + r) * HID + col;
            out_vis[o] = fmaxf(av[nt][r] + b1, 0.0f);
            out_txt[o] = fmaxf(at4[nt][r] + b2, 0.0f);
        }
    }
}

// ---------------- launch ----------------

extern "C" void kernel_launch(void* const* d_in, const int* in_sizes, int n_in,
                              void* d_out, int out_size, void* d_ws, size_t ws_size,
                              hipStream_t stream) {
    const float* x      = (const float*)d_in[0];
    const int*   ei     = (const int*)d_in[1];
    const float* gu     = (const float*)d_in[2];
    const float* w_feat = (const float*)d_in[3];
    const float* b_feat = (const float*)d_in[4];
    const float* w_hyp  = (const float*)d_in[5];
    const float* w_vis  = (const float*)d_in[6];
    const float* b_vis  = (const float*)d_in[7];
    const float* w_txt  = (const float*)d_in[8];
    const float* b_txt  = (const float*)d_in[9];
    float* out = (float*)d_out;

    const int* srcv = ei;
    const int* dstv = ei + E_EDGES;

    char* p = (char*)d_ws;
    int*   deg     = (int*)p;   p += (size_t)N_NODES * 4;
    int*   cnt     = (int*)p;   p += (size_t)N_NODES * 4;
    float* lat     = (float*)p; p += (size_t)HYP * HID * 4;  // kept for layout stability (unused)
    int*   rs      = (int*)p;   p += (size_t)(N_NODES + 1) * 4;
    float* dinv    = (float*)p; p += (size_t)N_NODES * 4;
    int2*  csr_sw  = (int2*)p;  p += (size_t)E_EDGES * 8;    // interleaved (src, w)
    float* x_emb   = (float*)p; p += (size_t)N_NODES * HID * 4;
    float* bufA    = (float*)p; p += (size_t)N_NODES * HID * 4;
    float* bufB    = (float*)p; p += (size_t)N_NODES * HID * 4;
    float* accb    = (float*)p; p += (size_t)N_NODES * HID * 4;
    float* Hm      = (float*)p; p += (size_t)N_NODES * HYP * 4;
    unsigned short* wfT  = (unsigned short*)p; p += (size_t)HID * IN_DIM * 2;  // [128][384]
    unsigned short* whT  = (unsigned short*)p; p += (size_t)HYP * HID * 2;     // [256][128]
    unsigned short* wvT  = (unsigned short*)p; p += (size_t)HID * HID * 2;     // [128][128]
    unsigned short* wtT  = (unsigned short*)p; p += (size_t)HID * HID * 2;     // [128][128]
    unsigned short* latT = (unsigned short*)p; p += (size_t)HID * HYP * 2;     // [128][256]
    int*   bsum    = (int*)p;   p += (size_t)SCAN_NB * 4;
    int*   bbase   = (int*)p;   p += (size_t)SCAN_NB * 4;

    // split-K partials for k_lat: 768 tiles x 64 KB = 50.33 MB.
    // bufA+bufB are contiguous (51.2 MB) and dead after the k_prop chain, so reuse them.
    float* latPart = bufA;

    // zero: deg, cnt, lat (contiguous at the head of ws)
    (void)hipMemsetAsync(d_ws, 0, (size_t)(2 * N_NODES + HYP * HID) * 4, stream);

    // fused weight transposes (1 launch instead of 4)
    k_cvt_all<<<448, 256, 0, stream>>>(w_feat, w_hyp, w_vis, w_txt, wfT, whT, wvT, wtT);

    // k_emb moved BEFORE the graph chain: only depends on x/wfT/b_feat.
    // (diagnostic: if its 78us was inherited drain from atomic-heavy k_fill, it drops here)
    k_emb<<<N_NODES / 16, 128, 0, stream>>>(x, wfT, b_feat, x_emb);

    k_deg<<<(E_EDGES + 255) / 256, 256, 0, stream>>>(dstv, deg);
    k_scan1<<<SCAN_NB, 256, 0, stream>>>(deg, bsum);
    k_scan2<<<1, 256, 0, stream>>>(bsum, bbase, rs);
    k_scan3<<<SCAN_NB, 256, 0, stream>>>(deg, bbase, rs, dinv);
    k_fill<<<(E_EDGES + 255) / 256, 256, 0, stream>>>(srcv, dstv, rs, cnt, dinv, csr_sw);

    k_prop<1><<<N_NODES / 8, 256, 0, stream>>>(x_emb, bufA, accb, rs, csr_sw);
    k_prop<0><<<N_NODES / 8, 256, 0, stream>>>(bufA, bufB, accb, rs, csr_sw);
    k_prop<0><<<N_NODES / 8, 256, 0, stream>>>(bufB, bufA, accb, rs, csr_sw);
    k_soft<<<N_NODES / 16, 64, 0, stream>>>(x_emb, whT, gu, Hm);
    k_lat<<<2 * LAT_KC, 256, 0, stream>>>(Hm, x_emb, latPart);
    k_lat_red<<<(HYP * HID) / 256, 256, 0, stream>>>(latPart, latT);
    k_tail<<<N_NODES / 16, 64, 0, stream>>>(Hm, latT, accb, wvT, b_vis, wtT, b_txt,
                                            out, out + (size_t)N_NODES * HID, out + (size_t)2 * N_NODES * HID);
}

// Round 6
// 619.129 us; speedup vs baseline: 1.8577x; 1.1259x over previous
//
#include <hip/hip_runtime.h>
#include <math.h>

#define N_NODES 50000
#define E_EDGES 600000
#define IN_DIM  384
#define HID     128
#define HYP     256

#define SCAN_NB ((N_NODES + 255) / 256)  // 196

typedef __attribute__((ext_vector_type(8))) short bf16x8;
typedef __attribute__((ext_vector_type(4))) float f32x4;
typedef _Float16 f16x4 __attribute__((ext_vector_type(4)));

__device__ __forceinline__ unsigned short f2bf(float f) {
    unsigned u = __builtin_bit_cast(unsigned, f);
    u = (u + 0x7FFFu + ((u >> 16) & 1u)) >> 16;
    return (unsigned short)u;
}

__device__ __forceinline__ bf16x8 cvt8(float4 p, float4 q) {
    bf16x8 a;
    a[0] = (short)f2bf(p.x); a[1] = (short)f2bf(p.y);
    a[2] = (short)f2bf(p.z); a[3] = (short)f2bf(p.w);
    a[4] = (short)f2bf(q.x); a[5] = (short)f2bf(q.y);
    a[6] = (short)f2bf(q.z); a[7] = (short)f2bf(q.w);
    return a;
}

// ---------------- graph preprocessing ----------------

__global__ void k_deg(const int* __restrict__ dst, int* __restrict__ deg) {
    int i = blockIdx.x * blockDim.x + threadIdx.x;
    if (i < E_EDGES) atomicAdd(&deg[dst[i]], 1);
}

// hierarchical scan, phase 1: per-block (256 elems) sum of deg -> bsum
__global__ __launch_bounds__(256) void k_scan1(const int* __restrict__ deg, int* __restrict__ bsum) {
    __shared__ int sh[256];
    int tid = threadIdx.x;
    int i = blockIdx.x * 256 + tid;
    sh[tid] = (i < N_NODES) ? deg[i] : 0;
    __syncthreads();
#pragma unroll
    for (int off = 128; off > 0; off >>= 1) {
        if (tid < off) sh[tid] += sh[tid + off];
        __syncthreads();
    }
    if (tid == 0) bsum[blockIdx.x] = sh[0];
}

// phase 2: single block scans the 196 block sums -> exclusive bbase
__global__ __launch_bounds__(256) void k_scan2(const int* __restrict__ bsum, int* __restrict__ bbase,
                                               int* __restrict__ row_start) {
    __shared__ int sh[256];
    int tid = threadIdx.x;
    int v = (tid < SCAN_NB) ? bsum[tid] : 0;
    sh[tid] = v;
    __syncthreads();
#pragma unroll
    for (int off = 1; off < 256; off <<= 1) {
        int t = (tid >= off) ? sh[tid - off] : 0;
        __syncthreads();
        sh[tid] += t;
        __syncthreads();
    }
    if (tid < SCAN_NB) bbase[tid] = sh[tid] - v;  // exclusive prefix of block sums
    if (tid == 0) row_start[N_NODES] = E_EDGES;
}

// phase 3: in-block exclusive scan + bbase -> row_start, dinv (coalesced)
__global__ __launch_bounds__(256) void k_scan3(const int* __restrict__ deg, const int* __restrict__ bbase,
                                               int* __restrict__ row_start, float* __restrict__ dinv) {
    __shared__ int sh[256];
    int tid = threadIdx.x;
    int i = blockIdx.x * 256 + tid;
    int d = (i < N_NODES) ? deg[i] : 0;
    sh[tid] = d;
    __syncthreads();
#pragma unroll
    for (int off = 1; off < 256; off <<= 1) {
        int t = (tid >= off) ? sh[tid - off] : 0;
        __syncthreads();
        sh[tid] += t;
        __syncthreads();
    }
    if (i < N_NODES) {
        row_start[i] = sh[tid] - d + bbase[blockIdx.x];
        dinv[i] = (d > 0) ? rsqrtf((float)d) : 0.0f;
    }
}

// fill CSR with interleaved (src, weight) pairs -> one 8B load per edge in k_prop
__global__ void k_fill(const int* __restrict__ src, const int* __restrict__ dst,
                       const int* __restrict__ row_start, int* __restrict__ cnt,
                       const float* __restrict__ dinv, int2* __restrict__ csr_sw) {
    int i = blockIdx.x * blockDim.x + threadIdx.x;
    if (i < E_EDGES) {
        int d = dst[i], s = src[i];
        int pos = row_start[d] + atomicAdd(&cnt[d], 1);
        csr_sw[pos] = make_int2(s, __float_as_int(dinv[s] * dinv[d]));
    }
}

// ---------------- fused weight transpose + fp32->bf16 (1 launch) ----------------

__global__ __launch_bounds__(256) void k_cvt_all(const float* __restrict__ wf, const float* __restrict__ wh,
                                                 const float* __restrict__ wv, const float* __restrict__ wt,
                                                 unsigned short* __restrict__ wfT, unsigned short* __restrict__ whT,
                                                 unsigned short* __restrict__ wvT, unsigned short* __restrict__ wtT) {
    int i = blockIdx.x * 256 + threadIdx.x;
    if (i < 49152) {
        int r = i >> 7, c = i & 127;                       // in [384][128]
        wfT[(size_t)c * IN_DIM + r] = f2bf(wf[i]);
    } else if (i < 49152 + 32768) {
        int j = i - 49152;
        int r = j >> 8, c = j & 255;                       // in [128][256]
        whT[(size_t)c * HID + r] = f2bf(wh[j]);
    } else if (i < 49152 + 32768 + 16384) {
        int j = i - 81920;
        int r = j >> 7, c = j & 127;                       // in [128][128]
        wvT[(size_t)c * HID + r] = f2bf(wv[j]);
    } else {
        int j = i - 98304;
        int r = j >> 7, c = j & 127;
        wtT[(size_t)c * HID + r] = f2bf(wt[j]);
    }
}

// ---------------- x_emb = x @ w_feat + b : MFMA, 2 waves/block split-K, 16 rows ----------------
// also emits fp16 copy (x_embh) for the layer-1 gather in k_prop.

__global__ __launch_bounds__(128) void k_emb(const float* __restrict__ x, const unsigned short* __restrict__ wfT,
                                             const float* __restrict__ bf_, float* __restrict__ x_emb,
                                             _Float16* __restrict__ x_embh) {
    __shared__ float red[16 * HID];  // 8 KB
    int tid = threadIdx.x;
    int wid = tid >> 6;            // K-half
    int lane = tid & 63;
    int l16 = lane & 15, quad = lane >> 4;
    int m0 = blockIdx.x * 16;
    const float* xrow = x + (size_t)(m0 + l16) * IN_DIM + wid * 192 + quad * 8;
    // preload the wave's entire K-half of its 16 rows: 6 kt x 2 float4 per lane
    float4 P[6], Q[6];
#pragma unroll
    for (int kt = 0; kt < 6; ++kt) {
        P[kt] = *reinterpret_cast<const float4*>(xrow + kt * 32);
        Q[kt] = *reinterpret_cast<const float4*>(xrow + kt * 32 + 4);
    }
    f32x4 acc[8];
#pragma unroll
    for (int nt = 0; nt < 8; ++nt) acc[nt] = (f32x4){0.f, 0.f, 0.f, 0.f};
#pragma unroll
    for (int kt = 0; kt < 6; ++kt) {
        bf16x8 a = cvt8(P[kt], Q[kt]);
#pragma unroll
        for (int nt = 0; nt < 8; ++nt) {
            bf16x8 b = *reinterpret_cast<const bf16x8*>(
                &wfT[(size_t)(nt * 16 + l16) * IN_DIM + wid * 192 + kt * 32 + quad * 8]);
            acc[nt] = __builtin_amdgcn_mfma_f32_16x16x32_bf16(a, b, acc[nt], 0, 0, 0);
        }
    }
    // cross-wave reduce: wave1 stages partial, wave0 adds + bias + store (fp32 + fp16)
    if (wid == 1) {
#pragma unroll
        for (int nt = 0; nt < 8; ++nt)
#pragma unroll
            for (int r = 0; r < 4; ++r)
                red[(quad * 4 + r) * HID + nt * 16 + l16] = acc[nt][r];
    }
    __syncthreads();
    if (wid == 0) {
#pragma unroll
        for (int nt = 0; nt < 8; ++nt) {
            int col = nt * 16 + l16;
            float bias = bf_[col];
#pragma unroll
            for (int r = 0; r < 4; ++r) {
                int lrow = quad * 4 + r;
                float v = acc[nt][r] + red[lrow * HID + col] + bias;
                size_t o = (size_t)(m0 + lrow) * HID + col;
                x_emb[o] = v;
                x_embh[o] = (_Float16)v;
            }
        }
    }
}

// ---------------- one LightGCN layer: fp16 gather (halved bytes), fp32 accumulate ----------------
// Round-6: the 3 k_prop layers move ~1.1 GB total (512B fp32 row gather per edge, L3-served).
// fp16 storage halves the gather and doubles L2 hit rate; accumulation stays fp32
// (fp16 eps 2^-11 on O(1) values -> ~1e-3 abs error, well under tolerance).
// INIT: accb = base[o] + a (base = x_emb fp32); else accb += a. LAST skips dead nxt store.

__device__ __forceinline__ void fma4h(float4& a, const f16x4 v, float s) {
    a.x = fmaf((float)v.x, s, a.x);
    a.y = fmaf((float)v.y, s, a.y);
    a.z = fmaf((float)v.z, s, a.z);
    a.w = fmaf((float)v.w, s, a.w);
}

template <int INIT, int LAST>
__global__ __launch_bounds__(256) void k_prop(const _Float16* __restrict__ curh, _Float16* __restrict__ nxth,
                                              const float* __restrict__ base, float* __restrict__ accb,
                                              const int* __restrict__ row_start,
                                              const int2* __restrict__ csr_sw) {
    int tid = threadIdx.x;
    int n = blockIdx.x * 8 + (tid >> 5);
    int c4 = (tid & 31) * 4;
    int s = row_start[n];
    int e = row_start[n + 1];
    float4 a[8];
#pragma unroll
    for (int k = 0; k < 8; ++k) a[k] = (float4){0.f, 0.f, 0.f, 0.f};
    for (int i = s; i < e; i += 8) {
        int2 pk[8];
        float wk[8];
#pragma unroll
        for (int k = 0; k < 8; ++k) {
            int j = i + k;
            pk[k] = csr_sw[(j < e) ? j : s];
            wk[k] = (j < e) ? __int_as_float(pk[k].y) : 0.0f;
        }
        f16x4 v[8];
#pragma unroll
        for (int k = 0; k < 8; ++k)
            v[k] = *reinterpret_cast<const f16x4*>(&curh[(size_t)pk[k].x * HID + c4]);
#pragma unroll
        for (int k = 0; k < 8; ++k) fma4h(a[k], v[k], wk[k]);
    }
    a[0].x += a[1].x; a[0].y += a[1].y; a[0].z += a[1].z; a[0].w += a[1].w;
    a[2].x += a[3].x; a[2].y += a[3].y; a[2].z += a[3].z; a[2].w += a[3].w;
    a[4].x += a[5].x; a[4].y += a[5].y; a[4].z += a[5].z; a[4].w += a[5].w;
    a[6].x += a[7].x; a[6].y += a[7].y; a[6].z += a[7].z; a[6].w += a[7].w;
    a[0].x += a[2].x; a[0].y += a[2].y; a[0].z += a[2].z; a[0].w += a[2].w;
    a[4].x += a[6].x; a[4].y += a[6].y; a[4].z += a[6].z; a[4].w += a[6].w;
    a[0].x += a[4].x; a[0].y += a[4].y; a[0].z += a[4].z; a[0].w += a[4].w;
    size_t o = (size_t)n * HID + c4;
    if (!LAST) {
        f16x4 oh;
        oh.x = (_Float16)a[0].x; oh.y = (_Float16)a[0].y;
        oh.z = (_Float16)a[0].z; oh.w = (_Float16)a[0].w;
        *reinterpret_cast<f16x4*>(&nxth[o]) = oh;
    }
    float4 ac = *reinterpret_cast<const float4*>(&base[o]);
    ac.x += a[0].x; ac.y += a[0].y; ac.z += a[0].z; ac.w += a[0].w;
    *reinterpret_cast<float4*>(&accb[o]) = ac;
}

// ---------------- Hm = softmax((x_emb @ w_hyper + g)/tau) : MFMA, 1 wave/block ----------------

__global__ __launch_bounds__(64) void k_soft(const float* __restrict__ x_emb, const unsigned short* __restrict__ whT,
                                             const float* __restrict__ gu, float* __restrict__ Hm) {
    int lane = threadIdx.x & 63;
    int l16 = lane & 15, quad = lane >> 4;
    int m0 = blockIdx.x * 16;
    const float* xrow = x_emb + (size_t)(m0 + l16) * HID + quad * 8;
    f32x4 acc[16];
#pragma unroll
    for (int nt = 0; nt < 16; ++nt) acc[nt] = (f32x4){0.f, 0.f, 0.f, 0.f};
#pragma unroll
    for (int kt = 0; kt < HID / 32; ++kt) {
        float4 p = *reinterpret_cast<const float4*>(xrow + kt * 32);
        float4 q = *reinterpret_cast<const float4*>(xrow + kt * 32 + 4);
        bf16x8 a = cvt8(p, q);
#pragma unroll
        for (int nt = 0; nt < 16; ++nt) {
            bf16x8 b = *reinterpret_cast<const bf16x8*>(&whT[(size_t)(nt * 16 + l16) * HID + kt * 32 + quad * 8]);
            acc[nt] = __builtin_amdgcn_mfma_f32_16x16x32_bf16(a, b, acc[nt], 0, 0, 0);
        }
    }
    // gumbel + 1/tau
#pragma unroll
    for (int nt = 0; nt < 16; ++nt) {
        int col = nt * 16 + l16;
#pragma unroll
        for (int r = 0; r < 4; ++r) {
            int row = m0 + quad * 4 + r;
            float u = gu[(size_t)row * HYP + col];
            float g = -logf(-logf(u + 1e-10f) + 1e-10f);
            acc[nt][r] = (acc[nt][r] + g) * 2.0f;
        }
    }
    // row max / sum over cols: per-lane over nt, then shfl over lane&15 group
    float mx[4] = {-3.4e38f, -3.4e38f, -3.4e38f, -3.4e38f};
#pragma unroll
    for (int nt = 0; nt < 16; ++nt)
#pragma unroll
        for (int r = 0; r < 4; ++r) mx[r] = fmaxf(mx[r], acc[nt][r]);
#pragma unroll
    for (int r = 0; r < 4; ++r) {
        mx[r] = fmaxf(mx[r], __shfl_xor(mx[r], 1));
        mx[r] = fmaxf(mx[r], __shfl_xor(mx[r], 2));
        mx[r] = fmaxf(mx[r], __shfl_xor(mx[r], 4));
        mx[r] = fmaxf(mx[r], __shfl_xor(mx[r], 8));
    }
    float sm[4] = {0.f, 0.f, 0.f, 0.f};
#pragma unroll
    for (int nt = 0; nt < 16; ++nt)
#pragma unroll
        for (int r = 0; r < 4; ++r) {
            float e = __expf(acc[nt][r] - mx[r]);
            acc[nt][r] = e;
            sm[r] += e;
        }
#pragma unroll
    for (int r = 0; r < 4; ++r) {
        sm[r] += __shfl_xor(sm[r], 1);
        sm[r] += __shfl_xor(sm[r], 2);
        sm[r] += __shfl_xor(sm[r], 4);
        sm[r] += __shfl_xor(sm[r], 8);
        sm[r] = 1.0f / sm[r];
    }
#pragma unroll
    for (int nt = 0; nt < 16; ++nt) {
        int col = nt * 16 + l16;
#pragma unroll
        for (int r = 0; r < 4; ++r)
            Hm[(size_t)(m0 + quad * 4 + r) * HYP + col] = acc[nt][r] * sm[r];
    }
}

// ---------------- lat = Hm^T @ x_emb : register-tiled outer product, split-K, ATOMIC-FREE ----------------

#define LAT_KC 384

__global__ __launch_bounds__(256) void k_lat(const float* __restrict__ Hm, const float* __restrict__ x_emb,
                                             float* __restrict__ part) {
    int htile = blockIdx.x & 1;
    int kc = blockIdx.x >> 1;
    const int chunk = (N_NODES + LAT_KC - 1) / LAT_KC;  // 131
    int start = kc * chunk;
    int end = min(N_NODES, start + chunk);
    int nn = end - start;  // may be <= 0 for the last couple of chunks
    int tid = threadIdx.x;
    int lh = (tid & 15) * 8;               // 8 consecutive h (within half) per thread
    int d = (tid >> 4) * 8;                // 8 consecutive d per thread
    const float* __restrict__ hp = Hm + (size_t)start * HYP + htile * 128 + lh;
    const float* __restrict__ xp = x_emb + (size_t)start * HID + d;
    float acc[8][8];
#pragma unroll
    for (int i = 0; i < 8; ++i)
#pragma unroll
        for (int j = 0; j < 8; ++j) acc[i][j] = 0.f;
#pragma unroll 2
    for (int n = 0; n < nn; ++n) {
        float4 a0 = *reinterpret_cast<const float4*>(hp);
        float4 a1 = *reinterpret_cast<const float4*>(hp + 4);
        float4 b0 = *reinterpret_cast<const float4*>(xp);
        float4 b1 = *reinterpret_cast<const float4*>(xp + 4);
        float av[8] = {a0.x, a0.y, a0.z, a0.w, a1.x, a1.y, a1.z, a1.w};
        float bv[8] = {b0.x, b0.y, b0.z, b0.w, b1.x, b1.y, b1.z, b1.w};
#pragma unroll
        for (int i = 0; i < 8; ++i)
#pragma unroll
            for (int j = 0; j < 8; ++j) acc[i][j] = fmaf(av[i], bv[j], acc[i][j]);
        hp += HYP;
        xp += HID;
    }
    float* __restrict__ pp = part + (size_t)blockIdx.x * (128 * 128) + (size_t)lh * 128 + d;
#pragma unroll
    for (int i = 0; i < 8; ++i) {
        float4 v0 = {acc[i][0], acc[i][1], acc[i][2], acc[i][3]};
        float4 v1 = {acc[i][4], acc[i][5], acc[i][6], acc[i][7]};
        *reinterpret_cast<float4*>(pp + i * 128) = v0;
        *reinterpret_cast<float4*>(pp + i * 128 + 4) = v1;
    }
}

// ---------------- reduce split-K partials -> latT (bf16, transposed) directly ----------------

__global__ __launch_bounds__(256) void k_lat_red(const float* __restrict__ part, unsigned short* __restrict__ latT) {
    int idx = blockIdx.x * 256 + threadIdx.x;  // [0, 32768)
    int d = idx & 127;
    int h = idx >> 7;
    int htile = h >> 7;
    int lh = h & 127;
    const float* __restrict__ p0 = part + (size_t)htile * (128 * 128) + (size_t)lh * 128 + d;
    const size_t kstride = (size_t)2 * 128 * 128;  // consecutive kc
    float s0 = 0.f, s1 = 0.f, s2 = 0.f, s3 = 0.f;
#pragma unroll 4
    for (int k = 0; k < LAT_KC; k += 4) {
        s0 += p0[(size_t)k * kstride];
        s1 += p0[(size_t)(k + 1) * kstride];
        s2 += p0[(size_t)(k + 2) * kstride];
        s3 += p0[(size_t)(k + 3) * kstride];
    }
    latT[(size_t)d * HYP + h] = f2bf((s0 + s1) + (s2 + s3));
}

// ---------------- tail: hyper = Hm @ lat; norm; final; two head GEMMs — MFMA, 1 wave/block ----------------

__global__ __launch_bounds__(64) void k_tail(const float* __restrict__ Hm, const unsigned short* __restrict__ latT,
                                             const float* __restrict__ accb,
                                             const unsigned short* __restrict__ wvT, const float* __restrict__ bv,
                                             const unsigned short* __restrict__ wtT, const float* __restrict__ bt,
                                             float* __restrict__ out_final, float* __restrict__ out_vis,
                                             float* __restrict__ out_txt) {
    __shared__ unsigned short fl[16 * HID];  // final tile, bf16, 4 KB
    int lane = threadIdx.x & 63;
    int l16 = lane & 15, quad = lane >> 4;
    int m0 = blockIdx.x * 16;
    const float* hrow = Hm + (size_t)(m0 + l16) * HYP + quad * 8;
    f32x4 acc[8];
#pragma unroll
    for (int nt = 0; nt < 8; ++nt) acc[nt] = (f32x4){0.f, 0.f, 0.f, 0.f};
#pragma unroll
    for (int kt = 0; kt < HYP / 32; ++kt) {
        float4 p = *reinterpret_cast<const float4*>(hrow + kt * 32);
        float4 q = *reinterpret_cast<const float4*>(hrow + kt * 32 + 4);
        bf16x8 a = cvt8(p, q);
#pragma unroll
        for (int nt = 0; nt < 8; ++nt) {
            bf16x8 b = *reinterpret_cast<const bf16x8*>(&latT[(size_t)(nt * 16 + l16) * HYP + kt * 32 + quad * 8]);
            acc[nt] = __builtin_amdgcn_mfma_f32_16x16x32_bf16(a, b, acc[nt], 0, 0, 0);
        }
    }
    // per-row L2 norm: rows = m0 + quad*4 + r; reduce over cols = nt x (lane&15)
    float ss[4] = {0.f, 0.f, 0.f, 0.f};
#pragma unroll
    for (int nt = 0; nt < 8; ++nt)
#pragma unroll
        for (int r = 0; r < 4; ++r) ss[r] = fmaf(acc[nt][r], acc[nt][r], ss[r]);
#pragma unroll
    for (int r = 0; r < 4; ++r) {
        ss[r] += __shfl_xor(ss[r], 1);
        ss[r] += __shfl_xor(ss[r], 2);
        ss[r] += __shfl_xor(ss[r], 4);
        ss[r] += __shfl_xor(ss[r], 8);
        ss[r] = 1.0f / fmaxf(sqrtf(ss[r]), 1e-12f);
    }
    // final = accb/4 + 0.1 * normalized; store + stage bf16 tile for head GEMMs
#pragma unroll
    for (int nt = 0; nt < 8; ++nt) {
        int col = nt * 16 + l16;
#pragma unroll
        for (int r = 0; r < 4; ++r) {
            int lrow = quad * 4 + r;
            size_t o = (size_t)(m0 + lrow) * HID + col;
            float f = accb[o] * 0.25f + 0.1f * (acc[nt][r] * ss[r]);
            out_final[o] = f;
            fl[lrow * HID + col] = f2bf(f);
        }
    }
    __syncthreads();
    // heads: A = final tile (LDS), B = wvT / wtT
    f32x4 av[8], at4[8];
#pragma unroll
    for (int nt = 0; nt < 8; ++nt) {
        av[nt] = (f32x4){0.f, 0.f, 0.f, 0.f};
        at4[nt] = (f32x4){0.f, 0.f, 0.f, 0.f};
    }
#pragma unroll
    for (int kt = 0; kt < HID / 32; ++kt) {
        bf16x8 a = *reinterpret_cast<const bf16x8*>(&fl[l16 * HID + kt * 32 + quad * 8]);
#pragma unroll
        for (int nt = 0; nt < 8; ++nt) {
            bf16x8 b1 = *reinterpret_cast<const bf16x8*>(&wvT[(size_t)(nt * 16 + l16) * HID + kt * 32 + quad * 8]);
            bf16x8 b2 = *reinterpret_cast<const bf16x8*>(&wtT[(size_t)(nt * 16 + l16) * HID + kt * 32 + quad * 8]);
            av[nt] = __builtin_amdgcn_mfma_f32_16x16x32_bf16(a, b1, av[nt], 0, 0, 0);
            at4[nt] = __builtin_amdgcn_mfma_f32_16x16x32_bf16(a, b2, at4[nt], 0, 0, 0);
        }
    }
#pragma unroll
    for (int nt = 0; nt < 8; ++nt) {
        int col = nt * 16 + l16;
        float b1 = bv[col], b2 = bt[col];
#pragma unroll
        for (int r = 0; r < 4; ++r) {
            size_t o = (size_t)(m0 + quad * 4 + r) * HID + col;
            out_vis[o] = fmaxf(av[nt][r] + b1, 0.0f);
            out_txt[o] = fmaxf(at4[nt][r] + b2, 0.0f);
        }
    }
}

// ---------------- launch ----------------

extern "C" void kernel_launch(void* const* d_in, const int* in_sizes, int n_in,
                              void* d_out, int out_size, void* d_ws, size_t ws_size,
                              hipStream_t stream) {
    const float* x      = (const float*)d_in[0];
    const int*   ei     = (const int*)d_in[1];
    const float* gu     = (const float*)d_in[2];
    const float* w_feat = (const float*)d_in[3];
    const float* b_feat = (const float*)d_in[4];
    const float* w_hyp  = (const float*)d_in[5];
    const float* w_vis  = (const float*)d_in[6];
    const float* b_vis  = (const float*)d_in[7];
    const float* w_txt  = (const float*)d_in[8];
    const float* b_txt  = (const float*)d_in[9];
    float* out = (float*)d_out;

    const int* srcv = ei;
    const int* dstv = ei + E_EDGES;

    char* p = (char*)d_ws;
    int*   deg     = (int*)p;   p += (size_t)N_NODES * 4;
    int*   cnt     = (int*)p;   p += (size_t)N_NODES * 4;
    float* lat     = (float*)p; p += (size_t)HYP * HID * 4;  // kept for layout stability (unused)
    int*   rs      = (int*)p;   p += (size_t)(N_NODES + 1) * 4;
    float* dinv    = (float*)p; p += (size_t)N_NODES * 4;
    int2*  csr_sw  = (int2*)p;  p += (size_t)E_EDGES * 8;    // interleaved (src, w)
    float* x_emb   = (float*)p; p += (size_t)N_NODES * HID * 4;
    float* bufA    = (float*)p; p += (size_t)N_NODES * HID * 4;
    float* bufB    = (float*)p; p += (size_t)N_NODES * HID * 4;
    float* accb    = (float*)p; p += (size_t)N_NODES * HID * 4;
    float* Hm      = (float*)p; p += (size_t)N_NODES * HYP * 4;
    unsigned short* wfT  = (unsigned short*)p; p += (size_t)HID * IN_DIM * 2;  // [128][384]
    unsigned short* whT  = (unsigned short*)p; p += (size_t)HYP * HID * 2;     // [256][128]
    unsigned short* wvT  = (unsigned short*)p; p += (size_t)HID * HID * 2;     // [128][128]
    unsigned short* wtT  = (unsigned short*)p; p += (size_t)HID * HID * 2;     // [128][128]
    unsigned short* latT = (unsigned short*)p; p += (size_t)HID * HYP * 2;     // [128][256]
    int*   bsum    = (int*)p;   p += (size_t)SCAN_NB * 4;
    int*   bbase   = (int*)p;   p += (size_t)SCAN_NB * 4;

    // fp16 propagation buffers live inside the (now oversized) fp32 bufA/bufB slots:
    //   bufAh = bufA[0 .. 12.8MB)        (layer-1 and layer-3 outputs)
    //   bufBh = bufB[0 .. 12.8MB)        (layer-2 output)
    //   x_embh = bufB[12.8MB .. 25.6MB)  (fp16 x_emb; only live until layer 1 completes)
    // latPart (50.33 MB split-K partials) still overlays bufA+bufB after the chain.
    _Float16* bufAh  = (_Float16*)bufA;
    _Float16* bufBh  = (_Float16*)bufB;
    _Float16* x_embh = (_Float16*)((char*)bufB + (size_t)N_NODES * HID * 2);
    float* latPart = bufA;

    // zero: deg, cnt, lat (contiguous at the head of ws)
    (void)hipMemsetAsync(d_ws, 0, (size_t)(2 * N_NODES + HYP * HID) * 4, stream);

    // fused weight transposes (1 launch)
    k_cvt_all<<<448, 256, 0, stream>>>(w_feat, w_hyp, w_vis, w_txt, wfT, whT, wvT, wtT);

    k_emb<<<N_NODES / 16, 128, 0, stream>>>(x, wfT, b_feat, x_emb, x_embh);

    k_deg<<<(E_EDGES + 255) / 256, 256, 0, stream>>>(dstv, deg);
    k_scan1<<<SCAN_NB, 256, 0, stream>>>(deg, bsum);
    k_scan2<<<1, 256, 0, stream>>>(bsum, bbase, rs);
    k_scan3<<<SCAN_NB, 256, 0, stream>>>(deg, bbase, rs, dinv);
    k_fill<<<(E_EDGES + 255) / 256, 256, 0, stream>>>(srcv, dstv, rs, cnt, dinv, csr_sw);

    k_prop<1, 0><<<N_NODES / 8, 256, 0, stream>>>(x_embh, bufAh, x_emb, accb, rs, csr_sw);
    k_prop<0, 0><<<N_NODES / 8, 256, 0, stream>>>(bufAh, bufBh, accb, accb, rs, csr_sw);
    k_prop<0, 1><<<N_NODES / 8, 256, 0, stream>>>(bufBh, bufAh, accb, accb, rs, csr_sw);
    k_soft<<<N_NODES / 16, 64, 0, stream>>>(x_emb, whT, gu, Hm);
    k_lat<<<2 * LAT_KC, 256, 0, stream>>>(Hm, x_emb, latPart);
    k_lat_red<<<(HYP * HID) / 256, 256, 0, stream>>>(latPart, latT);
    k_tail<<<N_NODES / 16, 64, 0, stream>>>(Hm, latT, accb, wvT, b_vis, wtT, b_txt,
                                            out, out + (size_t)N_NODES * HID, out + (size_t)2 * N_NODES * HID);
}

// Round 7
// 563.702 us; speedup vs baseline: 2.0404x; 1.0983x over previous
//
#include <hip/hip_runtime.h>
#include <math.h>

#define N_NODES 50000
#define E_EDGES 600000
#define IN_DIM  384
#define HID     128
#define HYP     256

#define SCAN_NB ((N_NODES + 255) / 256)   // 196
#define EMB_NB  (N_NODES / 16)            // 3125
#define DEG_NB  ((E_EDGES + 127) / 128)   // 4688

typedef __attribute__((ext_vector_type(8))) short bf16x8;
typedef __attribute__((ext_vector_type(4))) float f32x4;
typedef _Float16 f16x4 __attribute__((ext_vector_type(4)));
typedef _Float16 f16x8 __attribute__((ext_vector_type(8)));

__device__ __forceinline__ unsigned short f2bf(float f) {
    unsigned u = __builtin_bit_cast(unsigned, f);
    u = (u + 0x7FFFu + ((u >> 16) & 1u)) >> 16;
    return (unsigned short)u;
}

__device__ __forceinline__ bf16x8 cvt8(float4 p, float4 q) {
    bf16x8 a;
    a[0] = (short)f2bf(p.x); a[1] = (short)f2bf(p.y);
    a[2] = (short)f2bf(p.z); a[3] = (short)f2bf(p.w);
    a[4] = (short)f2bf(q.x); a[5] = (short)f2bf(q.y);
    a[6] = (short)f2bf(q.z); a[7] = (short)f2bf(q.w);
    return a;
}

// fp16x8 -> bf16x8 via float
__device__ __forceinline__ bf16x8 cvt8h(f16x8 h) {
    bf16x8 a;
#pragma unroll
    for (int i = 0; i < 8; ++i) a[i] = (short)f2bf((float)h[i]);
    return a;
}

// ---------------- graph preprocessing ----------------

// hierarchical scan, phase 1: per-block (256 elems) sum of deg -> bsum
__global__ __launch_bounds__(256) void k_scan1(const int* __restrict__ deg, int* __restrict__ bsum) {
    __shared__ int sh[256];
    int tid = threadIdx.x;
    int i = blockIdx.x * 256 + tid;
    sh[tid] = (i < N_NODES) ? deg[i] : 0;
    __syncthreads();
#pragma unroll
    for (int off = 128; off > 0; off >>= 1) {
        if (tid < off) sh[tid] += sh[tid + off];
        __syncthreads();
    }
    if (tid == 0) bsum[blockIdx.x] = sh[0];
}

// phase 2: single block scans the 196 block sums -> exclusive bbase
__global__ __launch_bounds__(256) void k_scan2(const int* __restrict__ bsum, int* __restrict__ bbase,
                                               int* __restrict__ row_start) {
    __shared__ int sh[256];
    int tid = threadIdx.x;
    int v = (tid < SCAN_NB) ? bsum[tid] : 0;
    sh[tid] = v;
    __syncthreads();
#pragma unroll
    for (int off = 1; off < 256; off <<= 1) {
        int t = (tid >= off) ? sh[tid - off] : 0;
        __syncthreads();
        sh[tid] += t;
        __syncthreads();
    }
    if (tid < SCAN_NB) bbase[tid] = sh[tid] - v;  // exclusive prefix of block sums
    if (tid == 0) row_start[N_NODES] = E_EDGES;
}

// phase 3: in-block exclusive scan + bbase -> row_start, dinv (coalesced)
__global__ __launch_bounds__(256) void k_scan3(const int* __restrict__ deg, const int* __restrict__ bbase,
                                               int* __restrict__ row_start, float* __restrict__ dinv) {
    __shared__ int sh[256];
    int tid = threadIdx.x;
    int i = blockIdx.x * 256 + tid;
    int d = (i < N_NODES) ? deg[i] : 0;
    sh[tid] = d;
    __syncthreads();
#pragma unroll
    for (int off = 1; off < 256; off <<= 1) {
        int t = (tid >= off) ? sh[tid - off] : 0;
        __syncthreads();
        sh[tid] += t;
        __syncthreads();
    }
    if (i < N_NODES) {
        row_start[i] = sh[tid] - d + bbase[blockIdx.x];
        dinv[i] = (d > 0) ? rsqrtf((float)d) : 0.0f;
    }
}

// fill CSR with interleaved (src, weight) pairs -> one 8B load per edge in k_prop
__global__ void k_fill(const int* __restrict__ src, const int* __restrict__ dst,
                       const int* __restrict__ row_start, int* __restrict__ cnt,
                       const float* __restrict__ dinv, int2* __restrict__ csr_sw) {
    int i = blockIdx.x * blockDim.x + threadIdx.x;
    if (i < E_EDGES) {
        int d = dst[i], s = src[i];
        int pos = row_start[d] + atomicAdd(&cnt[d], 1);
        csr_sw[pos] = make_int2(s, __float_as_int(dinv[s] * dinv[d]));
    }
}

// ---------------- fused weight transpose + fp32->bf16 (1 launch) ----------------

__global__ __launch_bounds__(256) void k_cvt_all(const float* __restrict__ wf, const float* __restrict__ wh,
                                                 const float* __restrict__ wv, const float* __restrict__ wt,
                                                 unsigned short* __restrict__ wfT, unsigned short* __restrict__ whT,
                                                 unsigned short* __restrict__ wvT, unsigned short* __restrict__ wtT) {
    int i = blockIdx.x * 256 + threadIdx.x;
    if (i < 49152) {
        int r = i >> 7, c = i & 127;                       // in [384][128]
        wfT[(size_t)c * IN_DIM + r] = f2bf(wf[i]);
    } else if (i < 49152 + 32768) {
        int j = i - 49152;
        int r = j >> 8, c = j & 255;                       // in [128][256]
        whT[(size_t)c * HID + r] = f2bf(wh[j]);
    } else if (i < 49152 + 32768 + 16384) {
        int j = i - 81920;
        int r = j >> 7, c = j & 127;                       // in [128][128]
        wvT[(size_t)c * HID + r] = f2bf(wv[j]);
    } else {
        int j = i - 98304;
        int r = j >> 7, c = j & 127;
        wtT[(size_t)c * HID + r] = f2bf(wt[j]);
    }
}

// ---------------- FUSED: x_emb GEMM (blocks < EMB_NB) || degree count (blocks >= EMB_NB) ----------
// k_emb part: MFMA, 2 waves/block split-K, 16 rows; stores fp16 ONLY (round-7: every consumer
// either bf16-rounds x_emb or tolerates fp16's 5e-4 rel — fp32 copy was 25.6 MB of dead write).
// k_deg part: independent atomic scatter; overlaps with k_emb's ~97%-idle pipes instead of
// serializing after it (saves its ~12us launch from the critical path).

__global__ __launch_bounds__(128) void k_embdeg(const float* __restrict__ x, const unsigned short* __restrict__ wfT,
                                                const float* __restrict__ bf_, _Float16* __restrict__ x_embh,
                                                const int* __restrict__ dst, int* __restrict__ deg) {
    int b = blockIdx.x;
    if (b >= EMB_NB) {
        int i = (b - EMB_NB) * 128 + threadIdx.x;
        if (i < E_EDGES) atomicAdd(&deg[dst[i]], 1);
        return;
    }
    __shared__ float red[16 * HID];  // 8 KB
    int tid = threadIdx.x;
    int wid = tid >> 6;            // K-half
    int lane = tid & 63;
    int l16 = lane & 15, quad = lane >> 4;
    int m0 = b * 16;
    const float* xrow = x + (size_t)(m0 + l16) * IN_DIM + wid * 192 + quad * 8;
    // preload the wave's entire K-half of its 16 rows: 6 kt x 2 float4 per lane
    float4 P[6], Q[6];
#pragma unroll
    for (int kt = 0; kt < 6; ++kt) {
        P[kt] = *reinterpret_cast<const float4*>(xrow + kt * 32);
        Q[kt] = *reinterpret_cast<const float4*>(xrow + kt * 32 + 4);
    }
    f32x4 acc[8];
#pragma unroll
    for (int nt = 0; nt < 8; ++nt) acc[nt] = (f32x4){0.f, 0.f, 0.f, 0.f};
#pragma unroll
    for (int kt = 0; kt < 6; ++kt) {
        bf16x8 a = cvt8(P[kt], Q[kt]);
#pragma unroll
        for (int nt = 0; nt < 8; ++nt) {
            bf16x8 bfr = *reinterpret_cast<const bf16x8*>(
                &wfT[(size_t)(nt * 16 + l16) * IN_DIM + wid * 192 + kt * 32 + quad * 8]);
            acc[nt] = __builtin_amdgcn_mfma_f32_16x16x32_bf16(a, bfr, acc[nt], 0, 0, 0);
        }
    }
    // cross-wave reduce: wave1 stages partial, wave0 adds + bias + fp16 store
    if (wid == 1) {
#pragma unroll
        for (int nt = 0; nt < 8; ++nt)
#pragma unroll
            for (int r = 0; r < 4; ++r)
                red[(quad * 4 + r) * HID + nt * 16 + l16] = acc[nt][r];
    }
    __syncthreads();
    if (wid == 0) {
#pragma unroll
        for (int nt = 0; nt < 8; ++nt) {
            int col = nt * 16 + l16;
            float bias = bf_[col];
#pragma unroll
            for (int r = 0; r < 4; ++r) {
                int lrow = quad * 4 + r;
                float v = acc[nt][r] + red[lrow * HID + col] + bias;
                x_embh[(size_t)(m0 + lrow) * HID + col] = (_Float16)v;
            }
        }
    }
}

// ---------------- one LightGCN layer: fp16 gather, fp32 accumulate ----------------
// INIT: accb = (float)curh[o] + a   (curh == x_embh)
// else: accb += a.  LAST skips dead nxt store.

__device__ __forceinline__ void fma4h(float4& a, const f16x4 v, float s) {
    a.x = fmaf((float)v.x, s, a.x);
    a.y = fmaf((float)v.y, s, a.y);
    a.z = fmaf((float)v.z, s, a.z);
    a.w = fmaf((float)v.w, s, a.w);
}

template <int INIT, int LAST>
__global__ __launch_bounds__(256) void k_prop(const _Float16* __restrict__ curh, _Float16* __restrict__ nxth,
                                              float* __restrict__ accb,
                                              const int* __restrict__ row_start,
                                              const int2* __restrict__ csr_sw) {
    int tid = threadIdx.x;
    int n = blockIdx.x * 8 + (tid >> 5);
    int c4 = (tid & 31) * 4;
    int s = row_start[n];
    int e = row_start[n + 1];
    float4 a[8];
#pragma unroll
    for (int k = 0; k < 8; ++k) a[k] = (float4){0.f, 0.f, 0.f, 0.f};
    for (int i = s; i < e; i += 8) {
        int2 pk[8];
        float wk[8];
#pragma unroll
        for (int k = 0; k < 8; ++k) {
            int j = i + k;
            pk[k] = csr_sw[(j < e) ? j : s];
            wk[k] = (j < e) ? __int_as_float(pk[k].y) : 0.0f;
        }
        f16x4 v[8];
#pragma unroll
        for (int k = 0; k < 8; ++k)
            v[k] = *reinterpret_cast<const f16x4*>(&curh[(size_t)pk[k].x * HID + c4]);
#pragma unroll
        for (int k = 0; k < 8; ++k) fma4h(a[k], v[k], wk[k]);
    }
    a[0].x += a[1].x; a[0].y += a[1].y; a[0].z += a[1].z; a[0].w += a[1].w;
    a[2].x += a[3].x; a[2].y += a[3].y; a[2].z += a[3].z; a[2].w += a[3].w;
    a[4].x += a[5].x; a[4].y += a[5].y; a[4].z += a[5].z; a[4].w += a[5].w;
    a[6].x += a[7].x; a[6].y += a[7].y; a[6].z += a[7].z; a[6].w += a[7].w;
    a[0].x += a[2].x; a[0].y += a[2].y; a[0].z += a[2].z; a[0].w += a[2].w;
    a[4].x += a[6].x; a[4].y += a[6].y; a[4].z += a[6].z; a[4].w += a[6].w;
    a[0].x += a[4].x; a[0].y += a[4].y; a[0].z += a[4].z; a[0].w += a[4].w;
    size_t o = (size_t)n * HID + c4;
    if (!LAST) {
        f16x4 oh;
        oh.x = (_Float16)a[0].x; oh.y = (_Float16)a[0].y;
        oh.z = (_Float16)a[0].z; oh.w = (_Float16)a[0].w;
        *reinterpret_cast<f16x4*>(&nxth[o]) = oh;
    }
    float4 ac;
    if (INIT) {
        f16x4 bh = *reinterpret_cast<const f16x4*>(&curh[o]);
        ac = make_float4((float)bh.x, (float)bh.y, (float)bh.z, (float)bh.w);
    } else {
        ac = *reinterpret_cast<const float4*>(&accb[o]);
    }
    ac.x += a[0].x; ac.y += a[0].y; ac.z += a[0].z; ac.w += a[0].w;
    *reinterpret_cast<float4*>(&accb[o]) = ac;
}

// ---------------- Hm = softmax((x_emb @ w_hyper + g)/tau) : MFMA, fp16 in/out ----------------

__global__ __launch_bounds__(64) void k_soft(const _Float16* __restrict__ x_embh,
                                             const unsigned short* __restrict__ whT,
                                             const float* __restrict__ gu, _Float16* __restrict__ Hmh) {
    int lane = threadIdx.x & 63;
    int l16 = lane & 15, quad = lane >> 4;
    int m0 = blockIdx.x * 16;
    const _Float16* xrow = x_embh + (size_t)(m0 + l16) * HID + quad * 8;
    f32x4 acc[16];
#pragma unroll
    for (int nt = 0; nt < 16; ++nt) acc[nt] = (f32x4){0.f, 0.f, 0.f, 0.f};
#pragma unroll
    for (int kt = 0; kt < HID / 32; ++kt) {
        f16x8 h = *reinterpret_cast<const f16x8*>(xrow + kt * 32);
        bf16x8 a = cvt8h(h);
#pragma unroll
        for (int nt = 0; nt < 16; ++nt) {
            bf16x8 b = *reinterpret_cast<const bf16x8*>(&whT[(size_t)(nt * 16 + l16) * HID + kt * 32 + quad * 8]);
            acc[nt] = __builtin_amdgcn_mfma_f32_16x16x32_bf16(a, b, acc[nt], 0, 0, 0);
        }
    }
    // gumbel + 1/tau
#pragma unroll
    for (int nt = 0; nt < 16; ++nt) {
        int col = nt * 16 + l16;
#pragma unroll
        for (int r = 0; r < 4; ++r) {
            int row = m0 + quad * 4 + r;
            float u = gu[(size_t)row * HYP + col];
            float g = -logf(-logf(u + 1e-10f) + 1e-10f);
            acc[nt][r] = (acc[nt][r] + g) * 2.0f;
        }
    }
    // row max / sum over cols: per-lane over nt, then shfl over lane&15 group
    float mx[4] = {-3.4e38f, -3.4e38f, -3.4e38f, -3.4e38f};
#pragma unroll
    for (int nt = 0; nt < 16; ++nt)
#pragma unroll
        for (int r = 0; r < 4; ++r) mx[r] = fmaxf(mx[r], acc[nt][r]);
#pragma unroll
    for (int r = 0; r < 4; ++r) {
        mx[r] = fmaxf(mx[r], __shfl_xor(mx[r], 1));
        mx[r] = fmaxf(mx[r], __shfl_xor(mx[r], 2));
        mx[r] = fmaxf(mx[r], __shfl_xor(mx[r], 4));
        mx[r] = fmaxf(mx[r], __shfl_xor(mx[r], 8));
    }
    float sm[4] = {0.f, 0.f, 0.f, 0.f};
#pragma unroll
    for (int nt = 0; nt < 16; ++nt)
#pragma unroll
        for (int r = 0; r < 4; ++r) {
            float e = __expf(acc[nt][r] - mx[r]);
            acc[nt][r] = e;
            sm[r] += e;
        }
#pragma unroll
    for (int r = 0; r < 4; ++r) {
        sm[r] += __shfl_xor(sm[r], 1);
        sm[r] += __shfl_xor(sm[r], 2);
        sm[r] += __shfl_xor(sm[r], 4);
        sm[r] += __shfl_xor(sm[r], 8);
        sm[r] = 1.0f / sm[r];
    }
#pragma unroll
    for (int nt = 0; nt < 16; ++nt) {
        int col = nt * 16 + l16;
#pragma unroll
        for (int r = 0; r < 4; ++r)
            Hmh[(size_t)(m0 + quad * 4 + r) * HYP + col] = (_Float16)(acc[nt][r] * sm[r]);
    }
}

// ---------------- lat = Hm^T @ x_emb : fp16 reads, fp32 outer product, split-K, ATOMIC-FREE ----

#define LAT_KC 384

__global__ __launch_bounds__(256) void k_lat(const _Float16* __restrict__ Hmh, const _Float16* __restrict__ x_embh,
                                             float* __restrict__ part) {
    int htile = blockIdx.x & 1;
    int kc = blockIdx.x >> 1;
    const int chunk = (N_NODES + LAT_KC - 1) / LAT_KC;  // 131
    int start = kc * chunk;
    int end = min(N_NODES, start + chunk);
    int nn = end - start;  // may be <= 0 for the last couple of chunks
    int tid = threadIdx.x;
    int lh = (tid & 15) * 8;               // 8 consecutive h (within half) per thread
    int d = (tid >> 4) * 8;                // 8 consecutive d per thread
    const _Float16* __restrict__ hp = Hmh + (size_t)start * HYP + htile * 128 + lh;
    const _Float16* __restrict__ xp = x_embh + (size_t)start * HID + d;
    float acc[8][8];
#pragma unroll
    for (int i = 0; i < 8; ++i)
#pragma unroll
        for (int j = 0; j < 8; ++j) acc[i][j] = 0.f;
#pragma unroll 2
    for (int n = 0; n < nn; ++n) {
        f16x8 ah = *reinterpret_cast<const f16x8*>(hp);
        f16x8 bh = *reinterpret_cast<const f16x8*>(xp);
        float av[8], bv[8];
#pragma unroll
        for (int i = 0; i < 8; ++i) { av[i] = (float)ah[i]; bv[i] = (float)bh[i]; }
#pragma unroll
        for (int i = 0; i < 8; ++i)
#pragma unroll
            for (int j = 0; j < 8; ++j) acc[i][j] = fmaf(av[i], bv[j], acc[i][j]);
        hp += HYP;
        xp += HID;
    }
    float* __restrict__ pp = part + (size_t)blockIdx.x * (128 * 128) + (size_t)lh * 128 + d;
#pragma unroll
    for (int i = 0; i < 8; ++i) {
        float4 v0 = {acc[i][0], acc[i][1], acc[i][2], acc[i][3]};
        float4 v1 = {acc[i][4], acc[i][5], acc[i][6], acc[i][7]};
        *reinterpret_cast<float4*>(pp + i * 128) = v0;
        *reinterpret_cast<float4*>(pp + i * 128 + 4) = v1;
    }
}

// ---------------- reduce split-K partials -> latT (bf16, transposed) directly ----------------

__global__ __launch_bounds__(256) void k_lat_red(const float* __restrict__ part, unsigned short* __restrict__ latT) {
    int idx = blockIdx.x * 256 + threadIdx.x;  // [0, 32768)
    int d = idx & 127;
    int h = idx >> 7;
    int htile = h >> 7;
    int lh = h & 127;
    const float* __restrict__ p0 = part + (size_t)htile * (128 * 128) + (size_t)lh * 128 + d;
    const size_t kstride = (size_t)2 * 128 * 128;  // consecutive kc
    float s0 = 0.f, s1 = 0.f, s2 = 0.f, s3 = 0.f;
#pragma unroll 4
    for (int k = 0; k < LAT_KC; k += 4) {
        s0 += p0[(size_t)k * kstride];
        s1 += p0[(size_t)(k + 1) * kstride];
        s2 += p0[(size_t)(k + 2) * kstride];
        s3 += p0[(size_t)(k + 3) * kstride];
    }
    latT[(size_t)d * HYP + h] = f2bf((s0 + s1) + (s2 + s3));
}

// ---------------- tail: hyper = Hm @ lat; norm; final; two head GEMMs — MFMA, 1 wave/block ----------------

__global__ __launch_bounds__(64) void k_tail(const _Float16* __restrict__ Hmh, const unsigned short* __restrict__ latT,
                                             const float* __restrict__ accb,
                                             const unsigned short* __restrict__ wvT, const float* __restrict__ bv,
                                             const unsigned short* __restrict__ wtT, const float* __restrict__ bt,
                                             float* __restrict__ out_final, float* __restrict__ out_vis,
                                             float* __restrict__ out_txt) {
    __shared__ unsigned short fl[16 * HID];  // final tile, bf16, 4 KB
    int lane = threadIdx.x & 63;
    int l16 = lane & 15, quad = lane >> 4;
    int m0 = blockIdx.x * 16;
    const _Float16* hrow = Hmh + (size_t)(m0 + l16) * HYP + quad * 8;
    f32x4 acc[8];
#pragma unroll
    for (int nt = 0; nt < 8; ++nt) acc[nt] = (f32x4){0.f, 0.f, 0.f, 0.f};
#pragma unroll
    for (int kt = 0; kt < HYP / 32; ++kt) {
        f16x8 h = *reinterpret_cast<const f16x8*>(hrow + kt * 32);
        bf16x8 a = cvt8h(h);
#pragma unroll
        for (int nt = 0; nt < 8; ++nt) {
            bf16x8 b = *reinterpret_cast<const bf16x8*>(&latT[(size_t)(nt * 16 + l16) * HYP + kt * 32 + quad * 8]);
            acc[nt] = __builtin_amdgcn_mfma_f32_16x16x32_bf16(a, b, acc[nt], 0, 0, 0);
        }
    }
    // per-row L2 norm: rows = m0 + quad*4 + r; reduce over cols = nt x (lane&15)
    float ss[4] = {0.f, 0.f, 0.f, 0.f};
#pragma unroll
    for (int nt = 0; nt < 8; ++nt)
#pragma unroll
        for (int r = 0; r < 4; ++r) ss[r] = fmaf(acc[nt][r], acc[nt][r], ss[r]);
#pragma unroll
    for (int r = 0; r < 4; ++r) {
        ss[r] += __shfl_xor(ss[r], 1);
        ss[r] += __shfl_xor(ss[r], 2);
        ss[r] += __shfl_xor(ss[r], 4);
        ss[r] += __shfl_xor(ss[r], 8);
        ss[r] = 1.0f / fmaxf(sqrtf(ss[r]), 1e-12f);
    }
    // final = accb/4 + 0.1 * normalized; store + stage bf16 tile for head GEMMs
#pragma unroll
    for (int nt = 0; nt < 8; ++nt) {
        int col = nt * 16 + l16;
#pragma unroll
        for (int r = 0; r < 4; ++r) {
            int lrow = quad * 4 + r;
            size_t o = (size_t)(m0 + lrow) * HID + col;
            float f = accb[o] * 0.25f + 0.1f * (acc[nt][r] * ss[r]);
            out_final[o] = f;
            fl[lrow * HID + col] = f2bf(f);
        }
    }
    __syncthreads();
    // heads: A = final tile (LDS), B = wvT / wtT
    f32x4 av[8], at4[8];
#pragma unroll
    for (int nt = 0; nt < 8; ++nt) {
        av[nt] = (f32x4){0.f, 0.f, 0.f, 0.f};
        at4[nt] = (f32x4){0.f, 0.f, 0.f, 0.f};
    }
#pragma unroll
    for (int kt = 0; kt < HID / 32; ++kt) {
        bf16x8 a = *reinterpret_cast<const bf16x8*>(&fl[l16 * HID + kt * 32 + quad * 8]);
#pragma unroll
        for (int nt = 0; nt < 8; ++nt) {
            bf16x8 b1 = *reinterpret_cast<const bf16x8*>(&wvT[(size_t)(nt * 16 + l16) * HID + kt * 32 + quad * 8]);
            bf16x8 b2 = *reinterpret_cast<const bf16x8*>(&wtT[(size_t)(nt * 16 + l16) * HID + kt * 32 + quad * 8]);
            av[nt] = __builtin_amdgcn_mfma_f32_16x16x32_bf16(a, b1, av[nt], 0, 0, 0);
            at4[nt] = __builtin_amdgcn_mfma_f32_16x16x32_bf16(a, b2, at4[nt], 0, 0, 0);
        }
    }
#pragma unroll
    for (int nt = 0; nt < 8; ++nt) {
        int col = nt * 16 + l16;
        float b1 = bv[col], b2 = bt[col];
#pragma unroll
        for (int r = 0; r < 4; ++r) {
            size_t o = (size_t)(m0 + quad * 4 + r) * HID + col;
            out_vis[o] = fmaxf(av[nt][r] + b1, 0.0f);
            out_txt[o] = fmaxf(at4[nt][r] + b2, 0.0f);
        }
    }
}

// ---------------- launch ----------------

extern "C" void kernel_launch(void* const* d_in, const int* in_sizes, int n_in,
                              void* d_out, int out_size, void* d_ws, size_t ws_size,
                              hipStream_t stream) {
    const float* x      = (const float*)d_in[0];
    const int*   ei     = (const int*)d_in[1];
    const float* gu     = (const float*)d_in[2];
    const float* w_feat = (const float*)d_in[3];
    const float* b_feat = (const float*)d_in[4];
    const float* w_hyp  = (const float*)d_in[5];
    const float* w_vis  = (const float*)d_in[6];
    const float* b_vis  = (const float*)d_in[7];
    const float* w_txt  = (const float*)d_in[8];
    const float* b_txt  = (const float*)d_in[9];
    float* out = (float*)d_out;

    const int* srcv = ei;
    const int* dstv = ei + E_EDGES;

    // 64B-aligned workspace carve (f16x8/int2 vector loads need natural alignment;
    // previous layout left slots at 4-mod-16 offsets).
    char* p = (char*)d_ws;
    auto carve = [&p](size_t bytes) {
        char* r = p;
        p += (bytes + 63) & ~(size_t)63;
        return r;
    };
    int*      deg     = (int*)carve((size_t)N_NODES * 4);
    int*      cnt     = (int*)carve((size_t)N_NODES * 4);
    int*      rs      = (int*)carve((size_t)(N_NODES + 1) * 4);
    float*    dinv    = (float*)carve((size_t)N_NODES * 4);
    int2*     csr_sw  = (int2*)carve((size_t)E_EDGES * 8);
    _Float16* x_embh  = (_Float16*)carve((size_t)N_NODES * HID * 2);
    float*    bufA    = (float*)carve((size_t)N_NODES * HID * 4);   // fp16 layer bufs + latPart overlay
    float*    bufB    = (float*)carve((size_t)N_NODES * HID * 4);
    float*    accb    = (float*)carve((size_t)N_NODES * HID * 4);
    _Float16* Hmh     = (_Float16*)carve((size_t)N_NODES * HYP * 2);
    unsigned short* wfT  = (unsigned short*)carve((size_t)HID * IN_DIM * 2);
    unsigned short* whT  = (unsigned short*)carve((size_t)HYP * HID * 2);
    unsigned short* wvT  = (unsigned short*)carve((size_t)HID * HID * 2);
    unsigned short* wtT  = (unsigned short*)carve((size_t)HID * HID * 2);
    unsigned short* latT = (unsigned short*)carve((size_t)HID * HYP * 2);
    int*      bsum    = (int*)carve((size_t)SCAN_NB * 4);
    int*      bbase   = (int*)carve((size_t)SCAN_NB * 4);

    // fp16 layer buffers live in the fp32-sized bufA/bufB slots; latPart (768 x 64KB
    // = 50.33 MB split-K partials) overlays bufA+bufB, which are dead after the prop chain.
    _Float16* bufAh = (_Float16*)bufA;
    _Float16* bufBh = (_Float16*)bufB;
    float* latPart = bufA;

    // zero: deg + cnt (first two carves, contiguous)
    (void)hipMemsetAsync(d_ws, 0, (size_t)2 * N_NODES * 4 + 128, stream);

    k_cvt_all<<<448, 256, 0, stream>>>(w_feat, w_hyp, w_vis, w_txt, wfT, whT, wvT, wtT);

    // fused: x_emb GEMM || degree count
    k_embdeg<<<EMB_NB + DEG_NB, 128, 0, stream>>>(x, wfT, b_feat, x_embh, dstv, deg);

    k_scan1<<<SCAN_NB, 256, 0, stream>>>(deg, bsum);
    k_scan2<<<1, 256, 0, stream>>>(bsum, bbase, rs);
    k_scan3<<<SCAN_NB, 256, 0, stream>>>(deg, bbase, rs, dinv);
    k_fill<<<(E_EDGES + 255) / 256, 256, 0, stream>>>(srcv, dstv, rs, cnt, dinv, csr_sw);

    k_prop<1, 0><<<N_NODES / 8, 256, 0, stream>>>(x_embh, bufAh, accb, rs, csr_sw);
    k_prop<0, 0><<<N_NODES / 8, 256, 0, stream>>>(bufAh, bufBh, accb, rs, csr_sw);
    k_prop<0, 1><<<N_NODES / 8, 256, 0, stream>>>(bufBh, bufAh, accb, rs, csr_sw);
    k_soft<<<N_NODES / 16, 64, 0, stream>>>(x_embh, whT, gu, Hmh);
    k_lat<<<2 * LAT_KC, 256, 0, stream>>>(Hmh, x_embh, latPart);
    k_lat_red<<<(HYP * HID) / 256, 256, 0, stream>>>(latPart, latT);
    k_tail<<<N_NODES / 16, 64, 0, stream>>>(Hmh, latT, accb, wvT, b_vis, wtT, b_txt,
                                            out, out + (size_t)N_NODES * HID, out + (size_t)2 * N_NODES * HID);
}